// Round 13
// baseline (173.353 us; speedup 1.0000x reference)
//
#include <hip/hip_runtime.h>
#include <stdint.h>

// MSA column attention, B=1 S=192 N=256 C=256 H=8 D=32
#define S_DIM 192
#define N_DIM 256
#define C_DIM 256
#define H_DIM 8
#define D_DIM 32
#define QKV_STRIDE (N_DIM * H_DIM * S_DIM * D_DIM)  // 12582912 elems (one of q/k/v)

typedef float f32x4 __attribute__((ext_vector_type(4)));
typedef float f32x16 __attribute__((ext_vector_type(16)));
typedef short bf16x8 __attribute__((ext_vector_type(8)));

__device__ __forceinline__ unsigned short f2bf(float f) {
  union { float f; unsigned u; } v; v.f = f;
  unsigned r = v.u + 0x7FFFu + ((v.u >> 16) & 1u);   // RNE
  return (unsigned short)(r >> 16);
}

__device__ __forceinline__ unsigned cvt_pk_bf16(float lo, float hi) {
  unsigned r;
  asm("v_cvt_pk_bf16_f32 %0, %1, %2" : "=v"(r) : "v"(lo), "v"(hi));
  return r;
}

__device__ __forceinline__ void gl2lds16(const void* g, void* l) {
  __builtin_amdgcn_global_load_lds(
      (const __attribute__((address_space(1))) unsigned int*)g,
      (__attribute__((address_space(3))) unsigned int*)l, 16, 0, 0);
}

// ---------- kernel 0: msa transpose+cvt, plus weight converts (merged) -----
__global__ __launch_bounds__(256) void k_prep(const float* __restrict__ msa,
                                              unsigned short* __restrict__ A,
                                              const float* __restrict__ wq,
                                              const float* __restrict__ wo,
                                              unsigned short* __restrict__ dq,
                                              unsigned short* __restrict__ do_) {
  int b = blockIdx.x;
  if (b < 12288) {
    int tid = b * 256 + threadIdx.x;   // over float4 units: TOK*64
    int token = tid >> 6;
    int c4 = tid & 63;
    int n = token / S_DIM;
    int s = token - n * S_DIM;
    float4 v = *(const float4*)(msa + ((size_t)(s * N_DIM + n) << 8) + (c4 << 2));
    ushort4 o;
    o.x = f2bf(v.x); o.y = f2bf(v.y); o.z = f2bf(v.z); o.w = f2bf(v.w);
    *(ushort4*)(A + ((size_t)token << 8) + (c4 << 2)) = o;
  } else {
    int tid = (b - 12288) * 256 + threadIdx.x;  // 65536 float4 units total
    const float* src; unsigned short* dst; int idx;
    if (tid < 49152) { src = wq; dst = dq; idx = tid; }
    else { src = wo; dst = do_; idx = tid - 49152; }
    float4 v = *(const float4*)(src + (size_t)idx * 4);
    ushort4 o;
    o.x = f2bf(v.x); o.y = f2bf(v.y); o.z = f2bf(v.z); o.w = f2bf(v.w);
    *(ushort4*)(dst + (size_t)idx * 4) = o;
  }
}

// ---------------- kernel 1: QKV GEMM  M=49152 N=768 K=256 ------------------
// R13: BARRIER-FREE direct-from-global operands. At K=256 the staged m97
// structure pays 2 barriers + full vmcnt drain per K-step for only 2x LDS
// reuse (R4/R8/R9: 46-61us, MfmaUtil <=16%). Here each lane loads its A/B
// frag straight from L2 (16 rows x 64B = 16 lines per instr), 8 loads feed
// 16 independent MFMAs, 1-deep register prefetch, zero LDS, zero barriers.
// Grid XCD-chunked bm-major (A-slice L2-hot across its 6 bn-sharers).
// Q,K stored packed [t3][nh][s][d] (C^T via swapped mfma -> ushort4 along d);
// V stored transposed [nh][d][s]. Epilogue byte-identical to R4.
__global__ __launch_bounds__(256, 3) void k_qkv(const unsigned short* __restrict__ A,
                                                const unsigned short* __restrict__ W,
                                                const float* __restrict__ bq,
                                                unsigned short* __restrict__ qkv) {
  const int tid = threadIdx.x;
  const int lane = tid & 63, wid = tid >> 6;
  const int l16 = lane & 15, lg = lane >> 4;
  const int wr = wid >> 1, wc = wid & 1;
  // XCD-chunked bm-major mapping: 2304 blocks = 8 XCDs x 288; o = bm*6+bn.
  const int p = blockIdx.x;
  const int o = (p & 7) * 288 + (p >> 3);
  const int bm0 = (o / 6) * 128;
  const int bn0 = (o % 6) * 128;

  const unsigned short* Ap = A + (size_t)(bm0 + wr * 64 + l16) * 256 + lg * 8;
  const unsigned short* Wp = W + (size_t)(bn0 + wc * 64 + l16) * 256 + lg * 8;

  f32x4 acc[4][4] = {};
  bf16x8 a[4], b[4], an[4], bn_[4];

  // prologue: ks=0 operands
#pragma unroll
  for (int m = 0; m < 4; m++) a[m] = *(const bf16x8*)(Ap + m * 16 * 256);
#pragma unroll
  for (int n2 = 0; n2 < 4; n2++) b[n2] = *(const bf16x8*)(Wp + n2 * 16 * 256);

#pragma unroll
  for (int ks = 0; ks < 8; ks++) {
    if (ks < 7) {
      const int k1 = (ks + 1) * 32;
#pragma unroll
      for (int m = 0; m < 4; m++) an[m] = *(const bf16x8*)(Ap + m * 16 * 256 + k1);
#pragma unroll
      for (int n2 = 0; n2 < 4; n2++) bn_[n2] = *(const bf16x8*)(Wp + n2 * 16 * 256 + k1);
    }
    if (bn0 < 512) {   // Q/K: compute C^T (row=j, col=token)
#pragma unroll
      for (int m = 0; m < 4; m++)
#pragma unroll
        for (int n2 = 0; n2 < 4; n2++)
          acc[m][n2] = __builtin_amdgcn_mfma_f32_16x16x32_bf16(b[n2], a[m], acc[m][n2], 0, 0, 0);
    } else {           // V: normal (row=token, col=j)
#pragma unroll
      for (int m = 0; m < 4; m++)
#pragma unroll
        for (int n2 = 0; n2 < 4; n2++)
          acc[m][n2] = __builtin_amdgcn_mfma_f32_16x16x32_bf16(a[m], b[n2], acc[m][n2], 0, 0, 0);
    }
#pragma unroll
    for (int m = 0; m < 4; m++) { a[m] = an[m]; b[m] = bn_[m]; }
  }

  const int t3 = bn0 >> 8;   // 0=Q, 1=K, 2=V
  if (t3 < 2) {
    // C^T: lane holds 4 consecutive j=(h,d0..d0+3) (rows lg*4+i), col = token (l16)
#pragma unroll
    for (int n2 = 0; n2 < 4; n2++) {
      int j0 = bn0 + wc * 64 + n2 * 16 + lg * 4;
      float4 b4 = *(const float4*)&bq[j0];
      int c0 = j0 & 255;                 // h*32 + d0
      int h = c0 >> 5, d0 = c0 & 31;
#pragma unroll
      for (int m = 0; m < 4; m++) {
        int token = bm0 + wr * 64 + m * 16 + l16;
        int n = token / S_DIM;
        int s = token - n * S_DIM;       // 16-lane group never crosses n (16|192)
        ushort4 o2;
        o2.x = f2bf(acc[m][n2][0] + b4.x);
        o2.y = f2bf(acc[m][n2][1] + b4.y);
        o2.z = f2bf(acc[m][n2][2] + b4.z);
        o2.w = f2bf(acc[m][n2][3] + b4.w);
        *(ushort4*)(qkv + (size_t)t3 * QKV_STRIDE +
                    ((size_t)((n * 8 + h) * 192 + s)) * 32 + d0) = o2;
      }
    }
  } else {
    // V^T [nh][d][s]: lane col = j -> (h,d); rows lg*4+i = 4 consecutive s
#pragma unroll
    for (int n2 = 0; n2 < 4; n2++) {
      int j = bn0 + wc * 64 + n2 * 16 + l16;
      int hd = j - 512;
      int h = hd >> 5, d = hd & 31;
      float bias = bq[j];
#pragma unroll
      for (int m = 0; m < 4; m++) {
        int t0 = bm0 + wr * 64 + m * 16 + lg * 4;
        int n = t0 / S_DIM;
        int s0 = t0 - n * S_DIM;     // 4-group never crosses n boundary (4 | 192)
        ushort4 o2;
        o2.x = f2bf(acc[m][n2][0] + bias);
        o2.y = f2bf(acc[m][n2][1] + bias);
        o2.z = f2bf(acc[m][n2][2] + bias);
        o2.w = f2bf(acc[m][n2][3] + bias);
        *(ushort4*)(qkv + (size_t)2 * QKV_STRIDE + ((size_t)(n * 8 + h) * 32 + d) * 192 + s0) = o2;
      }
    }
  }
}

// ---------------- kernel 2: attention, 6 waves (q-tiles) per (n,h) ---------
// Swapped QK^T at 32x32: S^T = mfma(K,Q) -> lane owns q-col = lane&31.
// Online softmax (defer-max), P->A-frag via cvt_pk + shfl_xor(32). No LDS.
// Q,K packed [nh][s][d]; V^T [nh][d][s]. 6 waves share K/V via L1/L2.
__global__ __launch_bounds__(384) void k_attn2(const unsigned short* __restrict__ qkv,
                                               unsigned short* __restrict__ attn_out) {
  const int lane = threadIdx.x & 63;
  const int l32 = lane & 31;
  const int hi = lane >> 5;
  const int qt = threadIdx.x >> 6;   // 0..5 (wave id = q-tile)
  const int nh = blockIdx.x;         // 0..2047
  const int n = nh >> 3, h = nh & 7;
  const unsigned short* Qp = qkv + (size_t)nh * (192 * 32);
  const unsigned short* Kp = qkv + (size_t)QKV_STRIDE + (size_t)nh * (192 * 32);
  const unsigned short* Vt = qkv + (size_t)2 * QKV_STRIDE + (size_t)nh * (32 * 192); // [d][192]
  const int q0 = qt * 32;

  // Q B-frags: lane holds col q = l32, k-dim d = hi*8+j (+16 per frag)
  bf16x8 bq0 = *(const bf16x8*)(Qp + (q0 + l32) * 32 + hi * 8);
  bf16x8 bq1 = *(const bf16x8*)(Qp + (q0 + l32) * 32 + 16 + hi * 8);

  f32x16 accO = {};
  float m_run = -1e30f, l_run = 0.f;
  const float scale = 0.17677669529663687f;          // 1/sqrt(32)
  const float DEFER = 8.0f / 0.17677669529663687f;   // raw-domain threshold

  // prefetch K and V tile 0
  bf16x8 ka0 = *(const bf16x8*)(Kp + l32 * 32 + hi * 8);
  bf16x8 ka1 = *(const bf16x8*)(Kp + l32 * 32 + 16 + hi * 8);
  bf16x8 va0 = *(const bf16x8*)(Vt + (size_t)l32 * 192 + hi * 8);
  bf16x8 va1 = *(const bf16x8*)(Vt + (size_t)l32 * 192 + 16 + hi * 8);

#pragma unroll
  for (int t = 0; t < 6; t++) {
    bf16x8 kn0, kn1, vn0, vn1;
    if (t < 5) {
      kn0 = *(const bf16x8*)(Kp + ((t + 1) * 32 + l32) * 32 + hi * 8);
      kn1 = *(const bf16x8*)(Kp + ((t + 1) * 32 + l32) * 32 + 16 + hi * 8);
      vn0 = *(const bf16x8*)(Vt + (size_t)l32 * 192 + (t + 1) * 32 + hi * 8);
      vn1 = *(const bf16x8*)(Vt + (size_t)l32 * 192 + (t + 1) * 32 + 16 + hi * 8);
    }
    // S^T[k][q]: reg r holds row k = (r&3)+8*(r>>2)+4*hi, col q = l32
    f32x16 sv = {};
    sv = __builtin_amdgcn_mfma_f32_32x32x16_bf16(ka0, bq0, sv, 0, 0, 0);
    sv = __builtin_amdgcn_mfma_f32_32x32x16_bf16(ka1, bq1, sv, 0, 0, 0);

    // tile max over full k column (own 16 + pair 16)
    float tmx = sv[0];
#pragma unroll
    for (int r = 1; r < 16; r++) tmx = fmaxf(tmx, sv[r]);
    tmx = fmaxf(tmx, __shfl_xor(tmx, 32));

    bool need = tmx > m_run + DEFER;
    if (__ballot(need)) {
      float m_new = fmaxf(m_run, tmx);
      float corr = __expf((m_run - m_new) * scale);
      l_run *= corr;
#pragma unroll
      for (int r = 0; r < 16; r++) {
        int qr = (r & 3) + 8 * (r >> 2) + 4 * hi;
        accO[r] *= __shfl(corr, qr);
      }
      m_run = m_new;
    }

    // exp + row-sum
    float ssum = 0.f;
#pragma unroll
    for (int r = 0; r < 16; r++) {
      float p2 = __expf((sv[r] - m_run) * scale);
      sv[r] = p2;
      ssum += p2;
    }
    ssum += __shfl_xor(ssum, 32);
    l_run += ssum;

    // pack P to bf16 pairs: a_g=pk[2g] rows g*8+hi*4+{0,1}; b_g=pk[2g+1] +{2,3}
    unsigned pk[8];
#pragma unroll
    for (int g = 0; g < 4; g++) {
      pk[2 * g]     = cvt_pk_bf16(sv[4 * g],     sv[4 * g + 1]);
      pk[2 * g + 1] = cvt_pk_bf16(sv[4 * g + 2], sv[4 * g + 3]);
    }

#pragma unroll
    for (int kh = 0; kh < 2; kh++) {
      // exchange: hi=0 lane needs pair's {a,b}_{2kh}; hi=1 needs pair's {a,b}_{2kh+1}
      unsigned sa = hi ? pk[4 * kh]     : pk[4 * kh + 2];
      unsigned sb = hi ? pk[4 * kh + 1] : pk[4 * kh + 3];
      unsigned pa = __shfl_xor((int)sa, 32);
      unsigned pb = __shfl_xor((int)sb, 32);
      union { unsigned u[4]; bf16x8 v; } af;
      af.u[0] = hi ? pa : pk[4 * kh];
      af.u[1] = hi ? pb : pk[4 * kh + 1];
      af.u[2] = hi ? pk[4 * kh + 2] : pa;
      af.u[3] = hi ? pk[4 * kh + 3] : pb;
      accO = __builtin_amdgcn_mfma_f32_32x32x16_bf16(af.v, kh ? va1 : va0, accO, 0, 0, 0);
    }
    ka0 = kn0; ka1 = kn1; va0 = vn0; va1 = vn1;
  }

  // epilogue: O[q][d] /= l[q]; store to attn_out[(s*256+n)*256 + h*32+d]
  float inv = 1.0f / l_run;
#pragma unroll
  for (int r = 0; r < 16; r++) {
    int qr = (r & 3) + 8 * (r >> 2) + 4 * hi;
    float v = accO[r] * __shfl(inv, qr);
    attn_out[((size_t)((q0 + qr) * 256 + n)) * 256 + h * 32 + l32] = f2bf(v);
  }
}

// ---------------- kernel 3: out-proj + residual + LayerNorm ----------------
// A = attn_out [token'=s*256+n][256] bf16, W=[256][256] bf16. BK=64 + swizzle.
__global__ __launch_bounds__(256) void k_out(const unsigned short* __restrict__ Aat,
                                             const unsigned short* __restrict__ W,
                                             const float* __restrict__ bo,
                                             const float* __restrict__ msa,
                                             const float* __restrict__ gamma,
                                             const float* __restrict__ beta,
                                             float* __restrict__ out) {
  __shared__ unsigned short As[128 * 64];
  __shared__ unsigned short Bs[256 * 64];
  const int tid = threadIdx.x;
  const int lane = tid & 63, wid = tid >> 6;
  const int l16 = lane & 15, lg = lane >> 4;
  const int bm0 = blockIdx.x * 128;
  const int lrow = lane >> 3, lchunk = lane & 7;
  const int sw = ((lchunk ^ lrow) * 8);

  f32x4 acc[2][16] = {};

  for (int ks = 0; ks < 4; ks++) {
    const int k0 = ks * 64;
    __syncthreads();
#pragma unroll
    for (int q = 0; q < 4; q++) {
      int base_row = wid * 32 + q * 8;
      gl2lds16(Aat + (size_t)(bm0 + base_row + lrow) * 256 + k0 + sw, &As[base_row * 64]);
    }
#pragma unroll
    for (int q = 0; q < 8; q++) {
      int base_row = wid * 64 + q * 8;
      gl2lds16(W + (size_t)(base_row + lrow) * 256 + k0 + sw, &Bs[base_row * 64]);
    }
    __syncthreads();
#pragma unroll
    for (int kk = 0; kk < 2; kk++) {
      const int xr = ((kk * 4 + lg) ^ (l16 & 7)) * 8;
      bf16x8 a[2];
#pragma unroll
      for (int m = 0; m < 2; m++)
        a[m] = *(const bf16x8*)&As[(wid * 32 + m * 16 + l16) * 64 + xr];
#pragma unroll
      for (int c = 0; c < 16; c++) {
        bf16x8 b = *(const bf16x8*)&Bs[(c * 16 + l16) * 64 + xr];
#pragma unroll
        for (int m = 0; m < 2; m++)
          acc[m][c] = __builtin_amdgcn_mfma_f32_16x16x32_bf16(a[m], b, acc[m][c], 0, 0, 0);
      }
    }
  }

  // epilogue: bias + residual, then LN per row (row spread over l16 x 16 frags)
#pragma unroll
  for (int m = 0; m < 2; m++) {
#pragma unroll
    for (int c = 0; c < 16; c++) {
      int col = c * 16 + l16;
      float bias = bo[col];
#pragma unroll
      for (int i = 0; i < 4; i++) {
        int row = bm0 + wid * 32 + m * 16 + lg * 4 + i;
        acc[m][c][i] += bias + msa[(size_t)row * 256 + col];
      }
    }
#pragma unroll
    for (int i = 0; i < 4; i++) {
      float s1 = 0.f, s2 = 0.f;
#pragma unroll
      for (int c = 0; c < 16; c++) { float x = acc[m][c][i]; s1 += x; s2 += x * x; }
      s1 += __shfl_xor(s1, 1); s2 += __shfl_xor(s2, 1);
      s1 += __shfl_xor(s1, 2); s2 += __shfl_xor(s2, 2);
      s1 += __shfl_xor(s1, 4); s2 += __shfl_xor(s2, 4);
      s1 += __shfl_xor(s1, 8); s2 += __shfl_xor(s2, 8);
      float mu = s1 * (1.0f / 256.0f);
      float var = s2 * (1.0f / 256.0f) - mu * mu;
      float rstd = rsqrtf(var + 1e-5f);
      int row = bm0 + wid * 32 + m * 16 + lg * 4 + i;
#pragma unroll
      for (int c = 0; c < 16; c++) {
        int col = c * 16 + l16;
        float y = (acc[m][c][i] - mu) * rstd * gamma[col] + beta[col];
        out[(size_t)row * 256 + col] = y;
      }
    }
  }
}

extern "C" void kernel_launch(void* const* d_in, const int* in_sizes, int n_in,
                              void* d_out, int out_size, void* d_ws, size_t ws_size,
                              hipStream_t stream) {
  const float* msa   = (const float*)d_in[0];
  const float* w_qkv = (const float*)d_in[1];
  const float* b_qkv = (const float*)d_in[2];
  const float* w_out = (const float*)d_in[3];
  const float* b_out = (const float*)d_in[4];
  const float* gamma = (const float*)d_in[5];
  const float* beta  = (const float*)d_in[6];
  float* out = (float*)d_out;

  char* ws = (char*)d_ws;
  // ws layout (bytes): A/attn_out 25165824 | Q 25165824 | K .. | V^T .. | wq 393216 | wo 131072
  unsigned short* A      = (unsigned short*)(ws);                      // reused as attn_out
  unsigned short* qkvbuf = (unsigned short*)(ws + 25165824ull);
  unsigned short* wq_bf  = (unsigned short*)(ws + 4ull * 25165824ull);
  unsigned short* wo_bf  = (unsigned short*)(ws + 4ull * 25165824ull + 393216ull);

  k_prep<<<12544, 256, 0, stream>>>(msa, A, w_qkv, w_out, wq_bf, wo_bf);
  k_qkv<<<2304, 256, 0, stream>>>(A, wq_bf, b_qkv, qkvbuf);
  k_attn2<<<2048, 384, 0, stream>>>(qkvbuf, A);
  k_out<<<384, 256, 0, stream>>>(A, wo_bf, b_out, msa, gamma, beta, out);
}

// Round 14
// 128.151 us; speedup vs baseline: 1.3527x; 1.3527x over previous
//
#include <hip/hip_runtime.h>
#include <stdint.h>

// MSA column attention, B=1 S=192 N=256 C=256 H=8 D=32
#define S_DIM 192
#define N_DIM 256
#define C_DIM 256
#define H_DIM 8
#define D_DIM 32
#define QKV_STRIDE (N_DIM * H_DIM * S_DIM * D_DIM)  // 12582912 elems (one of q/k/v)

typedef float f32x4 __attribute__((ext_vector_type(4)));
typedef float f32x16 __attribute__((ext_vector_type(16)));
typedef short bf16x8 __attribute__((ext_vector_type(8)));

__device__ __forceinline__ unsigned short f2bf(float f) {
  union { float f; unsigned u; } v; v.f = f;
  unsigned r = v.u + 0x7FFFu + ((v.u >> 16) & 1u);   // RNE
  return (unsigned short)(r >> 16);
}

__device__ __forceinline__ unsigned cvt_pk_bf16(float lo, float hi) {
  unsigned r;
  asm("v_cvt_pk_bf16_f32 %0, %1, %2" : "=v"(r) : "v"(lo), "v"(hi));
  return r;
}

__device__ __forceinline__ void gl2lds16(const void* g, void* l) {
  __builtin_amdgcn_global_load_lds(
      (const __attribute__((address_space(1))) unsigned int*)g,
      (__attribute__((address_space(3))) unsigned int*)l, 16, 0, 0);
}

// ---------- kernel 0: msa transpose+cvt, plus weight converts (merged) -----
__global__ __launch_bounds__(256) void k_prep(const float* __restrict__ msa,
                                              unsigned short* __restrict__ A,
                                              const float* __restrict__ wq,
                                              const float* __restrict__ wo,
                                              unsigned short* __restrict__ dq,
                                              unsigned short* __restrict__ do_) {
  int b = blockIdx.x;
  if (b < 12288) {
    int tid = b * 256 + threadIdx.x;   // over float4 units: TOK*64
    int token = tid >> 6;
    int c4 = tid & 63;
    int n = token / S_DIM;
    int s = token - n * S_DIM;
    float4 v = *(const float4*)(msa + ((size_t)(s * N_DIM + n) << 8) + (c4 << 2));
    ushort4 o;
    o.x = f2bf(v.x); o.y = f2bf(v.y); o.z = f2bf(v.z); o.w = f2bf(v.w);
    *(ushort4*)(A + ((size_t)token << 8) + (c4 << 2)) = o;
  } else {
    int tid = (b - 12288) * 256 + threadIdx.x;  // 65536 float4 units total
    const float* src; unsigned short* dst; int idx;
    if (tid < 49152) { src = wq; dst = dq; idx = tid; }
    else { src = wo; dst = do_; idx = tid - 49152; }
    float4 v = *(const float4*)(src + (size_t)idx * 4);
    ushort4 o;
    o.x = f2bf(v.x); o.y = f2bf(v.y); o.z = f2bf(v.z); o.w = f2bf(v.w);
    *(ushort4*)(dst + (size_t)idx * 4) = o;
  }
}

// ---------------- kernel 1: QKV GEMM  M=49152 N=768 K=256 ------------------
// R4-exact (measured best 46.4us): 128x128 tile, 4 waves, single-buffered
// BK=64, T2 swizzle (src-preswizzled gl2lds). Q,K stored packed [t3][nh][s][d]
// (C^T via swapped mfma -> ushort4 along d); V stored transposed [nh][d][s].
__global__ __launch_bounds__(256) void k_qkv(const unsigned short* __restrict__ A,
                                             const unsigned short* __restrict__ W,
                                             const float* __restrict__ bq,
                                             unsigned short* __restrict__ qkv) {
  __shared__ unsigned short As[128 * 64];
  __shared__ unsigned short Bs[128 * 64];
  const int tid = threadIdx.x;
  const int lane = tid & 63, wid = tid >> 6;
  const int l16 = lane & 15, lg = lane >> 4;
  const int wr = wid >> 1, wc = wid & 1;
  const int bm0 = blockIdx.x * 128;
  const int bn0 = blockIdx.y * 128;
  const int lrow = lane >> 3, lchunk = lane & 7;
  const int sw = ((lchunk ^ lrow) * 8);   // pre-swizzled source chunk (elems)

  f32x4 acc[4][4] = {};

  for (int ks = 0; ks < 4; ks++) {
    const int k0 = ks * 64;
    __syncthreads();
#pragma unroll
    for (int q = 0; q < 4; q++) {
      int base_row = wid * 32 + q * 8;
      gl2lds16(A + (size_t)(bm0 + base_row + lrow) * 256 + k0 + sw, &As[base_row * 64]);
    }
#pragma unroll
    for (int q = 0; q < 4; q++) {
      int base_row = wid * 32 + q * 8;
      gl2lds16(W + (size_t)(bn0 + base_row + lrow) * 256 + k0 + sw, &Bs[base_row * 64]);
    }
    __syncthreads();
#pragma unroll
    for (int kk = 0; kk < 2; kk++) {
      const int xr = ((kk * 4 + lg) ^ (l16 & 7)) * 8;   // swizzled read chunk
      bf16x8 a[4], b[4];
#pragma unroll
      for (int m = 0; m < 4; m++)
        a[m] = *(const bf16x8*)&As[(wr * 64 + m * 16 + l16) * 64 + xr];
#pragma unroll
      for (int n2 = 0; n2 < 4; n2++)
        b[n2] = *(const bf16x8*)&Bs[(wc * 64 + n2 * 16 + l16) * 64 + xr];
      if (bn0 < 512) {   // Q/K: compute C^T (row=j, col=token)
#pragma unroll
        for (int m = 0; m < 4; m++)
#pragma unroll
          for (int n2 = 0; n2 < 4; n2++)
            acc[m][n2] = __builtin_amdgcn_mfma_f32_16x16x32_bf16(b[n2], a[m], acc[m][n2], 0, 0, 0);
      } else {           // V: normal (row=token, col=j)
#pragma unroll
        for (int m = 0; m < 4; m++)
#pragma unroll
          for (int n2 = 0; n2 < 4; n2++)
            acc[m][n2] = __builtin_amdgcn_mfma_f32_16x16x32_bf16(a[m], b[n2], acc[m][n2], 0, 0, 0);
      }
    }
  }

  const int t3 = bn0 >> 8;   // 0=Q, 1=K, 2=V
  if (t3 < 2) {
    // C^T: lane holds 4 consecutive j=(h,d0..d0+3) (rows lg*4+i), col = token (l16)
#pragma unroll
    for (int n2 = 0; n2 < 4; n2++) {
      int j0 = bn0 + wc * 64 + n2 * 16 + lg * 4;
      float4 b4 = *(const float4*)&bq[j0];
      int c0 = j0 & 255;                 // h*32 + d0
      int h = c0 >> 5, d0 = c0 & 31;
#pragma unroll
      for (int m = 0; m < 4; m++) {
        int token = bm0 + wr * 64 + m * 16 + l16;
        int n = token / S_DIM;
        int s = token - n * S_DIM;       // 16-lane group never crosses n (16|192)
        ushort4 o;
        o.x = f2bf(acc[m][n2][0] + b4.x);
        o.y = f2bf(acc[m][n2][1] + b4.y);
        o.z = f2bf(acc[m][n2][2] + b4.z);
        o.w = f2bf(acc[m][n2][3] + b4.w);
        *(ushort4*)(qkv + (size_t)t3 * QKV_STRIDE +
                    ((size_t)((n * 8 + h) * 192 + s)) * 32 + d0) = o;
      }
    }
  } else {
    // V^T [nh][d][s]: lane col = j -> (h,d); rows lg*4+i = 4 consecutive s
#pragma unroll
    for (int n2 = 0; n2 < 4; n2++) {
      int j = bn0 + wc * 64 + n2 * 16 + l16;
      int hd = j - 512;
      int h = hd >> 5, d = hd & 31;
      float bias = bq[j];
#pragma unroll
      for (int m = 0; m < 4; m++) {
        int t0 = bm0 + wr * 64 + m * 16 + lg * 4;
        int n = t0 / S_DIM;
        int s0 = t0 - n * S_DIM;     // 4-group never crosses n boundary (4 | 192)
        ushort4 o;
        o.x = f2bf(acc[m][n2][0] + bias);
        o.y = f2bf(acc[m][n2][1] + bias);
        o.z = f2bf(acc[m][n2][2] + bias);
        o.w = f2bf(acc[m][n2][3] + bias);
        *(ushort4*)(qkv + (size_t)2 * QKV_STRIDE + ((size_t)(n * 8 + h) * 32 + d) * 192 + s0) = o;
      }
    }
  }
}

// ---------------- kernel 2: attention, 6 waves (q-tiles) per (n,h) ---------
// Swapped QK^T at 32x32: S^T = mfma(K,Q) -> lane owns q-col = lane&31.
// Online softmax, P->A-frag via cvt_pk + shfl_xor(32). No LDS.
// R14: 2-deep K/V prefetch (tiles t+1,t+2 in flight; static indices after
// full unroll), tree-shaped tile-max (depth 4 vs 15-chain), t=0 skips the
// guaranteed rescale (m_run init from tile 0).
__global__ __launch_bounds__(384) void k_attn2(const unsigned short* __restrict__ qkv,
                                               unsigned short* __restrict__ attn_out) {
  const int lane = threadIdx.x & 63;
  const int l32 = lane & 31;
  const int hi = lane >> 5;
  const int qt = threadIdx.x >> 6;   // 0..5 (wave id = q-tile)
  const int nh = blockIdx.x;         // 0..2047
  const int n = nh >> 3, h = nh & 7;
  const unsigned short* Qp = qkv + (size_t)nh * (192 * 32);
  const unsigned short* Kp = qkv + (size_t)QKV_STRIDE + (size_t)nh * (192 * 32);
  const unsigned short* Vt = qkv + (size_t)2 * QKV_STRIDE + (size_t)nh * (32 * 192); // [d][192]
  const int q0 = qt * 32;

  // Q B-frags: lane holds col q = l32, k-dim d = hi*8+j (+16 per frag)
  bf16x8 bq0 = *(const bf16x8*)(Qp + (q0 + l32) * 32 + hi * 8);
  bf16x8 bq1 = *(const bf16x8*)(Qp + (q0 + l32) * 32 + 16 + hi * 8);

  f32x16 accO = {};
  float m_run = 0.f, l_run = 0.f;
  const float scale = 0.17677669529663687f;          // 1/sqrt(32)
  const float DEFER = 8.0f / 0.17677669529663687f;   // raw-domain threshold

  // K/V tile register sets, 2-deep prefetch (indices static after unroll)
  bf16x8 kt[6][2], vt[6][2];
#pragma unroll
  for (int t0 = 0; t0 < 2; t0++) {
    kt[t0][0] = *(const bf16x8*)(Kp + (t0 * 32 + l32) * 32 + hi * 8);
    kt[t0][1] = *(const bf16x8*)(Kp + (t0 * 32 + l32) * 32 + 16 + hi * 8);
    vt[t0][0] = *(const bf16x8*)(Vt + (size_t)l32 * 192 + t0 * 32 + hi * 8);
    vt[t0][1] = *(const bf16x8*)(Vt + (size_t)l32 * 192 + t0 * 32 + 16 + hi * 8);
  }

#pragma unroll
  for (int t = 0; t < 6; t++) {
    if (t < 4) {
      kt[t + 2][0] = *(const bf16x8*)(Kp + ((t + 2) * 32 + l32) * 32 + hi * 8);
      kt[t + 2][1] = *(const bf16x8*)(Kp + ((t + 2) * 32 + l32) * 32 + 16 + hi * 8);
      vt[t + 2][0] = *(const bf16x8*)(Vt + (size_t)l32 * 192 + (t + 2) * 32 + hi * 8);
      vt[t + 2][1] = *(const bf16x8*)(Vt + (size_t)l32 * 192 + (t + 2) * 32 + 16 + hi * 8);
    }
    // S^T[k][q]: reg r holds row k = (r&3)+8*(r>>2)+4*hi, col q = l32
    f32x16 sv = {};
    sv = __builtin_amdgcn_mfma_f32_32x32x16_bf16(kt[t][0], bq0, sv, 0, 0, 0);
    sv = __builtin_amdgcn_mfma_f32_32x32x16_bf16(kt[t][1], bq1, sv, 0, 0, 0);

    // tile max over lane's 16 regs, tree-shaped (depth 4), then pair halves
    float m8[8];
#pragma unroll
    for (int r = 0; r < 8; r++) m8[r] = fmaxf(sv[r], sv[r + 8]);
    float m4a = fmaxf(m8[0], m8[1]), m4b = fmaxf(m8[2], m8[3]);
    float m4c = fmaxf(m8[4], m8[5]), m4d = fmaxf(m8[6], m8[7]);
    float tmx = fmaxf(fmaxf(m4a, m4b), fmaxf(m4c, m4d));
    tmx = fmaxf(tmx, __shfl_xor(tmx, 32));

    if (t == 0) {
      m_run = tmx;                     // accO==0, l_run==0: nothing to rescale
    } else if (__ballot(tmx > m_run + DEFER)) {
      float m_new = fmaxf(m_run, tmx);
      float corr = __expf((m_run - m_new) * scale);
      l_run *= corr;
#pragma unroll
      for (int r = 0; r < 16; r++) {
        int qr = (r & 3) + 8 * (r >> 2) + 4 * hi;
        accO[r] *= __shfl(corr, qr);
      }
      m_run = m_new;
    }

    // exp + row-sum
    float ssum = 0.f;
#pragma unroll
    for (int r = 0; r < 16; r++) {
      float p2 = __expf((sv[r] - m_run) * scale);
      sv[r] = p2;
      ssum += p2;
    }
    ssum += __shfl_xor(ssum, 32);
    l_run += ssum;

    // pack P to bf16 pairs: a_g=pk[2g] rows g*8+hi*4+{0,1}; b_g=pk[2g+1] +{2,3}
    unsigned pk[8];
#pragma unroll
    for (int g = 0; g < 4; g++) {
      pk[2 * g]     = cvt_pk_bf16(sv[4 * g],     sv[4 * g + 1]);
      pk[2 * g + 1] = cvt_pk_bf16(sv[4 * g + 2], sv[4 * g + 3]);
    }

#pragma unroll
    for (int kh = 0; kh < 2; kh++) {
      // exchange: hi=0 lane needs pair's {a,b}_{2kh}; hi=1 needs pair's {a,b}_{2kh+1}
      unsigned sa = hi ? pk[4 * kh]     : pk[4 * kh + 2];
      unsigned sb = hi ? pk[4 * kh + 1] : pk[4 * kh + 3];
      unsigned pa = __shfl_xor((int)sa, 32);
      unsigned pb = __shfl_xor((int)sb, 32);
      union { unsigned u[4]; bf16x8 v; } af;
      af.u[0] = hi ? pa : pk[4 * kh];
      af.u[1] = hi ? pb : pk[4 * kh + 1];
      af.u[2] = hi ? pk[4 * kh + 2] : pa;
      af.u[3] = hi ? pk[4 * kh + 3] : pb;
      accO = __builtin_amdgcn_mfma_f32_32x32x16_bf16(af.v, vt[t][kh], accO, 0, 0, 0);
    }
  }

  // epilogue: O[q][d] /= l[q]; store to attn_out[(s*256+n)*256 + h*32+d]
  float inv = 1.0f / l_run;
#pragma unroll
  for (int r = 0; r < 16; r++) {
    int qr = (r & 3) + 8 * (r >> 2) + 4 * hi;
    float v = accO[r] * __shfl(inv, qr);
    attn_out[((size_t)((q0 + qr) * 256 + n)) * 256 + h * 32 + l32] = f2bf(v);
  }
}

// ---------------- kernel 3: out-proj + residual + LayerNorm ----------------
// A = attn_out [token'=s*256+n][256] bf16, W=[256][256] bf16. BK=64 + swizzle.
__global__ __launch_bounds__(256) void k_out(const unsigned short* __restrict__ Aat,
                                             const unsigned short* __restrict__ W,
                                             const float* __restrict__ bo,
                                             const float* __restrict__ msa,
                                             const float* __restrict__ gamma,
                                             const float* __restrict__ beta,
                                             float* __restrict__ out) {
  __shared__ unsigned short As[128 * 64];
  __shared__ unsigned short Bs[256 * 64];
  const int tid = threadIdx.x;
  const int lane = tid & 63, wid = tid >> 6;
  const int l16 = lane & 15, lg = lane >> 4;
  const int bm0 = blockIdx.x * 128;
  const int lrow = lane >> 3, lchunk = lane & 7;
  const int sw = ((lchunk ^ lrow) * 8);

  f32x4 acc[2][16] = {};

  for (int ks = 0; ks < 4; ks++) {
    const int k0 = ks * 64;
    __syncthreads();
#pragma unroll
    for (int q = 0; q < 4; q++) {
      int base_row = wid * 32 + q * 8;
      gl2lds16(Aat + (size_t)(bm0 + base_row + lrow) * 256 + k0 + sw, &As[base_row * 64]);
    }
#pragma unroll
    for (int q = 0; q < 8; q++) {
      int base_row = wid * 64 + q * 8;
      gl2lds16(W + (size_t)(base_row + lrow) * 256 + k0 + sw, &Bs[base_row * 64]);
    }
    __syncthreads();
#pragma unroll
    for (int kk = 0; kk < 2; kk++) {
      const int xr = ((kk * 4 + lg) ^ (l16 & 7)) * 8;
      bf16x8 a[2];
#pragma unroll
      for (int m = 0; m < 2; m++)
        a[m] = *(const bf16x8*)&As[(wid * 32 + m * 16 + l16) * 64 + xr];
#pragma unroll
      for (int c = 0; c < 16; c++) {
        bf16x8 b = *(const bf16x8*)&Bs[(c * 16 + l16) * 64 + xr];
#pragma unroll
        for (int m = 0; m < 2; m++)
          acc[m][c] = __builtin_amdgcn_mfma_f32_16x16x32_bf16(a[m], b, acc[m][c], 0, 0, 0);
      }
    }
  }

  // epilogue: bias + residual, then LN per row (row spread over l16 x 16 frags)
#pragma unroll
  for (int m = 0; m < 2; m++) {
#pragma unroll
    for (int c = 0; c < 16; c++) {
      int col = c * 16 + l16;
      float bias = bo[col];
#pragma unroll
      for (int i = 0; i < 4; i++) {
        int row = bm0 + wid * 32 + m * 16 + lg * 4 + i;
        acc[m][c][i] += bias + msa[(size_t)row * 256 + col];
      }
    }
#pragma unroll
    for (int i = 0; i < 4; i++) {
      float s1 = 0.f, s2 = 0.f;
#pragma unroll
      for (int c = 0; c < 16; c++) { float x = acc[m][c][i]; s1 += x; s2 += x * x; }
      s1 += __shfl_xor(s1, 1); s2 += __shfl_xor(s2, 1);
      s1 += __shfl_xor(s1, 2); s2 += __shfl_xor(s2, 2);
      s1 += __shfl_xor(s1, 4); s2 += __shfl_xor(s2, 4);
      s1 += __shfl_xor(s1, 8); s2 += __shfl_xor(s2, 8);
      float mu = s1 * (1.0f / 256.0f);
      float var = s2 * (1.0f / 256.0f) - mu * mu;
      float rstd = rsqrtf(var + 1e-5f);
      int row = bm0 + wid * 32 + m * 16 + lg * 4 + i;
#pragma unroll
      for (int c = 0; c < 16; c++) {
        int col = c * 16 + l16;
        float y = (acc[m][c][i] - mu) * rstd * gamma[col] + beta[col];
        out[(size_t)row * 256 + col] = y;
      }
    }
  }
}

extern "C" void kernel_launch(void* const* d_in, const int* in_sizes, int n_in,
                              void* d_out, int out_size, void* d_ws, size_t ws_size,
                              hipStream_t stream) {
  const float* msa   = (const float*)d_in[0];
  const float* w_qkv = (const float*)d_in[1];
  const float* b_qkv = (const float*)d_in[2];
  const float* w_out = (const float*)d_in[3];
  const float* b_out = (const float*)d_in[4];
  const float* gamma = (const float*)d_in[5];
  const float* beta  = (const float*)d_in[6];
  float* out = (float*)d_out;

  char* ws = (char*)d_ws;
  // ws layout (bytes): A/attn_out 25165824 | Q 25165824 | K .. | V^T .. | wq 393216 | wo 131072
  unsigned short* A      = (unsigned short*)(ws);                      // reused as attn_out
  unsigned short* qkvbuf = (unsigned short*)(ws + 25165824ull);
  unsigned short* wq_bf  = (unsigned short*)(ws + 4ull * 25165824ull);
  unsigned short* wo_bf  = (unsigned short*)(ws + 4ull * 25165824ull + 393216ull);

  k_prep<<<12544, 256, 0, stream>>>(msa, A, w_qkv, w_out, wq_bf, wo_bf);
  dim3 g2(384, 6);
  k_qkv<<<g2, 256, 0, stream>>>(A, wq_bf, b_qkv, qkvbuf);
  k_attn2<<<2048, 384, 0, stream>>>(qkvbuf, A);
  k_out<<<384, 256, 0, stream>>>(A, wo_bf, b_out, msa, gamma, beta, out);
}

// Round 15
// 126.445 us; speedup vs baseline: 1.3710x; 1.0135x over previous
//
#include <hip/hip_runtime.h>
#include <stdint.h>

// MSA column attention, B=1 S=192 N=256 C=256 H=8 D=32
#define S_DIM 192
#define N_DIM 256
#define C_DIM 256
#define H_DIM 8
#define D_DIM 32
#define QKV_STRIDE (N_DIM * H_DIM * S_DIM * D_DIM)  // 12582912 elems (one of q/k/v)

typedef float f32x4 __attribute__((ext_vector_type(4)));
typedef float f32x16 __attribute__((ext_vector_type(16)));
typedef short bf16x8 __attribute__((ext_vector_type(8)));

__device__ __forceinline__ unsigned short f2bf(float f) {
  union { float f; unsigned u; } v; v.f = f;
  unsigned r = v.u + 0x7FFFu + ((v.u >> 16) & 1u);   // RNE
  return (unsigned short)(r >> 16);
}

__device__ __forceinline__ unsigned cvt_pk_bf16(float lo, float hi) {
  unsigned r;
  asm("v_cvt_pk_bf16_f32 %0, %1, %2" : "=v"(r) : "v"(lo), "v"(hi));
  return r;
}

__device__ __forceinline__ void gl2lds16(const void* g, void* l) {
  __builtin_amdgcn_global_load_lds(
      (const __attribute__((address_space(1))) unsigned int*)g,
      (__attribute__((address_space(3))) unsigned int*)l, 16, 0, 0);
}

// ---------- kernel 0: msa transpose+cvt, plus weight converts (merged) -----
__global__ __launch_bounds__(256) void k_prep(const float* __restrict__ msa,
                                              unsigned short* __restrict__ A,
                                              const float* __restrict__ wq,
                                              const float* __restrict__ wo,
                                              unsigned short* __restrict__ dq,
                                              unsigned short* __restrict__ do_) {
  int b = blockIdx.x;
  if (b < 12288) {
    int tid = b * 256 + threadIdx.x;   // over float4 units: TOK*64
    int token = tid >> 6;
    int c4 = tid & 63;
    int n = token / S_DIM;
    int s = token - n * S_DIM;
    float4 v = *(const float4*)(msa + ((size_t)(s * N_DIM + n) << 8) + (c4 << 2));
    ushort4 o;
    o.x = f2bf(v.x); o.y = f2bf(v.y); o.z = f2bf(v.z); o.w = f2bf(v.w);
    *(ushort4*)(A + ((size_t)token << 8) + (c4 << 2)) = o;
  } else {
    int tid = (b - 12288) * 256 + threadIdx.x;  // 65536 float4 units total
    const float* src; unsigned short* dst; int idx;
    if (tid < 49152) { src = wq; dst = dq; idx = tid; }
    else { src = wo; dst = do_; idx = tid - 49152; }
    float4 v = *(const float4*)(src + (size_t)idx * 4);
    ushort4 o;
    o.x = f2bf(v.x); o.y = f2bf(v.y); o.z = f2bf(v.z); o.w = f2bf(v.w);
    *(ushort4*)(dst + (size_t)idx * 4) = o;
  }
}

// ---------------- kernel 1: QKV GEMM  M=49152 N=768 K=256 ------------------
// R4-exact (measured best 46.4us): 128x128 tile, 4 waves, single-buffered
// BK=64, T2 swizzle (src-preswizzled gl2lds). Q,K stored packed [t3][nh][s][d]
// (C^T via swapped mfma -> ushort4 along d); V stored transposed [nh][d][s].
__global__ __launch_bounds__(256) void k_qkv(const unsigned short* __restrict__ A,
                                             const unsigned short* __restrict__ W,
                                             const float* __restrict__ bq,
                                             unsigned short* __restrict__ qkv) {
  __shared__ unsigned short As[128 * 64];
  __shared__ unsigned short Bs[128 * 64];
  const int tid = threadIdx.x;
  const int lane = tid & 63, wid = tid >> 6;
  const int l16 = lane & 15, lg = lane >> 4;
  const int wr = wid >> 1, wc = wid & 1;
  const int bm0 = blockIdx.x * 128;
  const int bn0 = blockIdx.y * 128;
  const int lrow = lane >> 3, lchunk = lane & 7;
  const int sw = ((lchunk ^ lrow) * 8);   // pre-swizzled source chunk (elems)

  f32x4 acc[4][4] = {};

  for (int ks = 0; ks < 4; ks++) {
    const int k0 = ks * 64;
    __syncthreads();
#pragma unroll
    for (int q = 0; q < 4; q++) {
      int base_row = wid * 32 + q * 8;
      gl2lds16(A + (size_t)(bm0 + base_row + lrow) * 256 + k0 + sw, &As[base_row * 64]);
    }
#pragma unroll
    for (int q = 0; q < 4; q++) {
      int base_row = wid * 32 + q * 8;
      gl2lds16(W + (size_t)(bn0 + base_row + lrow) * 256 + k0 + sw, &Bs[base_row * 64]);
    }
    __syncthreads();
#pragma unroll
    for (int kk = 0; kk < 2; kk++) {
      const int xr = ((kk * 4 + lg) ^ (l16 & 7)) * 8;   // swizzled read chunk
      bf16x8 a[4], b[4];
#pragma unroll
      for (int m = 0; m < 4; m++)
        a[m] = *(const bf16x8*)&As[(wr * 64 + m * 16 + l16) * 64 + xr];
#pragma unroll
      for (int n2 = 0; n2 < 4; n2++)
        b[n2] = *(const bf16x8*)&Bs[(wc * 64 + n2 * 16 + l16) * 64 + xr];
      if (bn0 < 512) {   // Q/K: compute C^T (row=j, col=token)
#pragma unroll
        for (int m = 0; m < 4; m++)
#pragma unroll
          for (int n2 = 0; n2 < 4; n2++)
            acc[m][n2] = __builtin_amdgcn_mfma_f32_16x16x32_bf16(b[n2], a[m], acc[m][n2], 0, 0, 0);
      } else {           // V: normal (row=token, col=j)
#pragma unroll
        for (int m = 0; m < 4; m++)
#pragma unroll
          for (int n2 = 0; n2 < 4; n2++)
            acc[m][n2] = __builtin_amdgcn_mfma_f32_16x16x32_bf16(a[m], b[n2], acc[m][n2], 0, 0, 0);
      }
    }
  }

  const int t3 = bn0 >> 8;   // 0=Q, 1=K, 2=V
  if (t3 < 2) {
    // C^T: lane holds 4 consecutive j=(h,d0..d0+3) (rows lg*4+i), col = token (l16)
#pragma unroll
    for (int n2 = 0; n2 < 4; n2++) {
      int j0 = bn0 + wc * 64 + n2 * 16 + lg * 4;
      float4 b4 = *(const float4*)&bq[j0];
      int c0 = j0 & 255;                 // h*32 + d0
      int h = c0 >> 5, d0 = c0 & 31;
#pragma unroll
      for (int m = 0; m < 4; m++) {
        int token = bm0 + wr * 64 + m * 16 + l16;
        int n = token / S_DIM;
        int s = token - n * S_DIM;       // 16-lane group never crosses n (16|192)
        ushort4 o;
        o.x = f2bf(acc[m][n2][0] + b4.x);
        o.y = f2bf(acc[m][n2][1] + b4.y);
        o.z = f2bf(acc[m][n2][2] + b4.z);
        o.w = f2bf(acc[m][n2][3] + b4.w);
        *(ushort4*)(qkv + (size_t)t3 * QKV_STRIDE +
                    ((size_t)((n * 8 + h) * 192 + s)) * 32 + d0) = o;
      }
    }
  } else {
    // V^T [nh][d][s]: lane col = j -> (h,d); rows lg*4+i = 4 consecutive s
#pragma unroll
    for (int n2 = 0; n2 < 4; n2++) {
      int j = bn0 + wc * 64 + n2 * 16 + l16;
      int hd = j - 512;
      int h = hd >> 5, d = hd & 31;
      float bias = bq[j];
#pragma unroll
      for (int m = 0; m < 4; m++) {
        int t0 = bm0 + wr * 64 + m * 16 + lg * 4;
        int n = t0 / S_DIM;
        int s0 = t0 - n * S_DIM;     // 4-group never crosses n boundary (4 | 192)
        ushort4 o;
        o.x = f2bf(acc[m][n2][0] + bias);
        o.y = f2bf(acc[m][n2][1] + bias);
        o.z = f2bf(acc[m][n2][2] + bias);
        o.w = f2bf(acc[m][n2][3] + bias);
        *(ushort4*)(qkv + (size_t)2 * QKV_STRIDE + ((size_t)(n * 8 + h) * 32 + d) * 192 + s0) = o;
      }
    }
  }
}

// ---------------- kernel 2: attention, 6 waves (q-tiles) per (n,h) ---------
// Swapped QK^T at 32x32: S^T = mfma(K,Q) -> lane owns q-col = lane&31.
// Online softmax (defer-max), P->A-frag via cvt_pk + shfl_xor(32). No LDS.
// Q,K packed [nh][s][d]; V^T [nh][d][s]. 6 waves share K/V via L1/L2.
// (R12-exact version: K+V 1-deep prefetch, unrolled.)
__global__ __launch_bounds__(384) void k_attn2(const unsigned short* __restrict__ qkv,
                                               unsigned short* __restrict__ attn_out) {
  const int lane = threadIdx.x & 63;
  const int l32 = lane & 31;
  const int hi = lane >> 5;
  const int qt = threadIdx.x >> 6;   // 0..5 (wave id = q-tile)
  const int nh = blockIdx.x;         // 0..2047
  const int n = nh >> 3, h = nh & 7;
  const unsigned short* Qp = qkv + (size_t)nh * (192 * 32);
  const unsigned short* Kp = qkv + (size_t)QKV_STRIDE + (size_t)nh * (192 * 32);
  const unsigned short* Vt = qkv + (size_t)2 * QKV_STRIDE + (size_t)nh * (32 * 192); // [d][192]
  const int q0 = qt * 32;

  // Q B-frags: lane holds col q = l32, k-dim d = hi*8+j (+16 per frag)
  bf16x8 bq0 = *(const bf16x8*)(Qp + (q0 + l32) * 32 + hi * 8);
  bf16x8 bq1 = *(const bf16x8*)(Qp + (q0 + l32) * 32 + 16 + hi * 8);

  f32x16 accO = {};
  float m_run = -1e30f, l_run = 0.f;
  const float scale = 0.17677669529663687f;          // 1/sqrt(32)
  const float DEFER = 8.0f / 0.17677669529663687f;   // raw-domain threshold

  // prefetch K and V tile 0
  bf16x8 ka0 = *(const bf16x8*)(Kp + l32 * 32 + hi * 8);
  bf16x8 ka1 = *(const bf16x8*)(Kp + l32 * 32 + 16 + hi * 8);
  bf16x8 va0 = *(const bf16x8*)(Vt + (size_t)l32 * 192 + hi * 8);
  bf16x8 va1 = *(const bf16x8*)(Vt + (size_t)l32 * 192 + 16 + hi * 8);

#pragma unroll
  for (int t = 0; t < 6; t++) {
    bf16x8 kn0, kn1, vn0, vn1;
    if (t < 5) {
      kn0 = *(const bf16x8*)(Kp + ((t + 1) * 32 + l32) * 32 + hi * 8);
      kn1 = *(const bf16x8*)(Kp + ((t + 1) * 32 + l32) * 32 + 16 + hi * 8);
      vn0 = *(const bf16x8*)(Vt + (size_t)l32 * 192 + (t + 1) * 32 + hi * 8);
      vn1 = *(const bf16x8*)(Vt + (size_t)l32 * 192 + (t + 1) * 32 + 16 + hi * 8);
    }
    // S^T[k][q]: reg r holds row k = (r&3)+8*(r>>2)+4*hi, col q = l32
    f32x16 sv = {};
    sv = __builtin_amdgcn_mfma_f32_32x32x16_bf16(ka0, bq0, sv, 0, 0, 0);
    sv = __builtin_amdgcn_mfma_f32_32x32x16_bf16(ka1, bq1, sv, 0, 0, 0);

    // tile max over full k column (own 16 + pair 16)
    float tmx = sv[0];
#pragma unroll
    for (int r = 1; r < 16; r++) tmx = fmaxf(tmx, sv[r]);
    tmx = fmaxf(tmx, __shfl_xor(tmx, 32));

    bool need = tmx > m_run + DEFER;
    if (__ballot(need)) {
      float m_new = fmaxf(m_run, tmx);
      float corr = __expf((m_run - m_new) * scale);
      l_run *= corr;
#pragma unroll
      for (int r = 0; r < 16; r++) {
        int qr = (r & 3) + 8 * (r >> 2) + 4 * hi;
        accO[r] *= __shfl(corr, qr);
      }
      m_run = m_new;
    }

    // exp + row-sum
    float ssum = 0.f;
#pragma unroll
    for (int r = 0; r < 16; r++) {
      float p2 = __expf((sv[r] - m_run) * scale);
      sv[r] = p2;
      ssum += p2;
    }
    ssum += __shfl_xor(ssum, 32);
    l_run += ssum;

    // pack P to bf16 pairs: a_g=pk[2g] rows g*8+hi*4+{0,1}; b_g=pk[2g+1] +{2,3}
    unsigned pk[8];
#pragma unroll
    for (int g = 0; g < 4; g++) {
      pk[2 * g]     = cvt_pk_bf16(sv[4 * g],     sv[4 * g + 1]);
      pk[2 * g + 1] = cvt_pk_bf16(sv[4 * g + 2], sv[4 * g + 3]);
    }

#pragma unroll
    for (int kh = 0; kh < 2; kh++) {
      // exchange: hi=0 lane needs pair's {a,b}_{2kh}; hi=1 needs pair's {a,b}_{2kh+1}
      unsigned sa = hi ? pk[4 * kh]     : pk[4 * kh + 2];
      unsigned sb = hi ? pk[4 * kh + 1] : pk[4 * kh + 3];
      unsigned pa = __shfl_xor((int)sa, 32);
      unsigned pb = __shfl_xor((int)sb, 32);
      union { unsigned u[4]; bf16x8 v; } af;
      af.u[0] = hi ? pa : pk[4 * kh];
      af.u[1] = hi ? pb : pk[4 * kh + 1];
      af.u[2] = hi ? pk[4 * kh + 2] : pa;
      af.u[3] = hi ? pk[4 * kh + 3] : pb;
      accO = __builtin_amdgcn_mfma_f32_32x32x16_bf16(af.v, kh ? va1 : va0, accO, 0, 0, 0);
    }
    ka0 = kn0; ka1 = kn1; va0 = vn0; va1 = vn1;
  }

  // epilogue: O[q][d] /= l[q]; store to attn_out[(s*256+n)*256 + h*32+d]
  float inv = 1.0f / l_run;
#pragma unroll
  for (int r = 0; r < 16; r++) {
    int qr = (r & 3) + 8 * (r >> 2) + 4 * hi;
    float v = accO[r] * __shfl(inv, qr);
    attn_out[((size_t)((q0 + qr) * 256 + n)) * 256 + h * 32 + l32] = f2bf(v);
  }
}

// ---------------- kernel 3: out-proj + residual + LayerNorm ----------------
// A = attn_out [token'=s*256+n][256] bf16, W=[256][256] bf16. BK=64 + swizzle.
// R15: BM 128->64 (grid 384->768, 3 blocks/CU balanced; LDS 48->40KB; acc
// halves to 16 f32x4) — R14's 384-block grid was 1.5 blocks/CU, TLP-starved.
// BN stays 256 (full row in-block, required by the fused in-register LN).
__global__ __launch_bounds__(256) void k_out(const unsigned short* __restrict__ Aat,
                                             const unsigned short* __restrict__ W,
                                             const float* __restrict__ bo,
                                             const float* __restrict__ msa,
                                             const float* __restrict__ gamma,
                                             const float* __restrict__ beta,
                                             float* __restrict__ out) {
  __shared__ unsigned short As[64 * 64];
  __shared__ unsigned short Bs[256 * 64];
  const int tid = threadIdx.x;
  const int lane = tid & 63, wid = tid >> 6;
  const int l16 = lane & 15, lg = lane >> 4;
  const int bm0 = blockIdx.x * 64;
  const int lrow = lane >> 3, lchunk = lane & 7;
  const int sw = ((lchunk ^ lrow) * 8);

  f32x4 acc[16] = {};

  for (int ks = 0; ks < 4; ks++) {
    const int k0 = ks * 64;
    __syncthreads();
#pragma unroll
    for (int q = 0; q < 2; q++) {
      int base_row = q * 32 + wid * 8;
      gl2lds16(Aat + (size_t)(bm0 + base_row + lrow) * 256 + k0 + sw, &As[base_row * 64]);
    }
#pragma unroll
    for (int q = 0; q < 8; q++) {
      int base_row = wid * 64 + q * 8;
      gl2lds16(W + (size_t)(base_row + lrow) * 256 + k0 + sw, &Bs[base_row * 64]);
    }
    __syncthreads();
#pragma unroll
    for (int kk = 0; kk < 2; kk++) {
      const int xr = ((kk * 4 + lg) ^ (l16 & 7)) * 8;
      bf16x8 a = *(const bf16x8*)&As[(wid * 16 + l16) * 64 + xr];
#pragma unroll
      for (int c = 0; c < 16; c++) {
        bf16x8 b = *(const bf16x8*)&Bs[(c * 16 + l16) * 64 + xr];
        acc[c] = __builtin_amdgcn_mfma_f32_16x16x32_bf16(a, b, acc[c], 0, 0, 0);
      }
    }
  }

  // epilogue: bias + residual, then LN per row (row spread over l16 x 16 frags)
#pragma unroll
  for (int c = 0; c < 16; c++) {
    int col = c * 16 + l16;
    float bias = bo[col];
#pragma unroll
    for (int i = 0; i < 4; i++) {
      int row = bm0 + wid * 16 + lg * 4 + i;
      acc[c][i] += bias + msa[(size_t)row * 256 + col];
    }
  }
#pragma unroll
  for (int i = 0; i < 4; i++) {
    float s1 = 0.f, s2 = 0.f;
#pragma unroll
    for (int c = 0; c < 16; c++) { float x = acc[c][i]; s1 += x; s2 += x * x; }
    s1 += __shfl_xor(s1, 1); s2 += __shfl_xor(s2, 1);
    s1 += __shfl_xor(s1, 2); s2 += __shfl_xor(s2, 2);
    s1 += __shfl_xor(s1, 4); s2 += __shfl_xor(s2, 4);
    s1 += __shfl_xor(s1, 8); s2 += __shfl_xor(s2, 8);
    float mu = s1 * (1.0f / 256.0f);
    float var = s2 * (1.0f / 256.0f) - mu * mu;
    float rstd = rsqrtf(var + 1e-5f);
    int row = bm0 + wid * 16 + lg * 4 + i;
#pragma unroll
    for (int c = 0; c < 16; c++) {
      int col = c * 16 + l16;
      float y = (acc[c][i] - mu) * rstd * gamma[col] + beta[col];
      out[(size_t)row * 256 + col] = y;
    }
  }
}

extern "C" void kernel_launch(void* const* d_in, const int* in_sizes, int n_in,
                              void* d_out, int out_size, void* d_ws, size_t ws_size,
                              hipStream_t stream) {
  const float* msa   = (const float*)d_in[0];
  const float* w_qkv = (const float*)d_in[1];
  const float* b_qkv = (const float*)d_in[2];
  const float* w_out = (const float*)d_in[3];
  const float* b_out = (const float*)d_in[4];
  const float* gamma = (const float*)d_in[5];
  const float* beta  = (const float*)d_in[6];
  float* out = (float*)d_out;

  char* ws = (char*)d_ws;
  // ws layout (bytes): A/attn_out 25165824 | Q 25165824 | K .. | V^T .. | wq 393216 | wo 131072
  unsigned short* A      = (unsigned short*)(ws);                      // reused as attn_out
  unsigned short* qkvbuf = (unsigned short*)(ws + 25165824ull);
  unsigned short* wq_bf  = (unsigned short*)(ws + 4ull * 25165824ull);
  unsigned short* wo_bf  = (unsigned short*)(ws + 4ull * 25165824ull + 393216ull);

  k_prep<<<12544, 256, 0, stream>>>(msa, A, w_qkv, w_out, wq_bf, wo_bf);
  dim3 g2(384, 6);
  k_qkv<<<g2, 256, 0, stream>>>(A, wq_bf, b_qkv, qkvbuf);
  k_attn2<<<2048, 384, 0, stream>>>(qkvbuf, A);
  k_out<<<768, 256, 0, stream>>>(A, wo_bf, b_out, msa, gamma, beta, out);
}

// Round 16
// 122.647 us; speedup vs baseline: 1.4134x; 1.0310x over previous
//
#include <hip/hip_runtime.h>
#include <stdint.h>

// MSA column attention, B=1 S=192 N=256 C=256 H=8 D=32
#define S_DIM 192
#define N_DIM 256
#define C_DIM 256
#define H_DIM 8
#define D_DIM 32
#define QKV_STRIDE (N_DIM * H_DIM * S_DIM * D_DIM)  // 12582912 elems (one of q/k/v)

typedef float f32x4 __attribute__((ext_vector_type(4)));
typedef float f32x16 __attribute__((ext_vector_type(16)));
typedef short bf16x8 __attribute__((ext_vector_type(8)));

__device__ __forceinline__ unsigned short f2bf(float f) {
  union { float f; unsigned u; } v; v.f = f;
  unsigned r = v.u + 0x7FFFu + ((v.u >> 16) & 1u);   // RNE
  return (unsigned short)(r >> 16);
}

__device__ __forceinline__ unsigned cvt_pk_bf16(float lo, float hi) {
  unsigned r;
  asm("v_cvt_pk_bf16_f32 %0, %1, %2" : "=v"(r) : "v"(lo), "v"(hi));
  return r;
}

__device__ __forceinline__ void gl2lds16(const void* g, void* l) {
  __builtin_amdgcn_global_load_lds(
      (const __attribute__((address_space(1))) unsigned int*)g,
      (__attribute__((address_space(3))) unsigned int*)l, 16, 0, 0);
}

// ---------- kernel 0: msa transpose+cvt, plus weight converts (merged) -----
__global__ __launch_bounds__(256) void k_prep(const float* __restrict__ msa,
                                              unsigned short* __restrict__ A,
                                              const float* __restrict__ wq,
                                              const float* __restrict__ wo,
                                              unsigned short* __restrict__ dq,
                                              unsigned short* __restrict__ do_) {
  int b = blockIdx.x;
  if (b < 12288) {
    int tid = b * 256 + threadIdx.x;   // over float4 units: TOK*64
    int token = tid >> 6;
    int c4 = tid & 63;
    int n = token / S_DIM;
    int s = token - n * S_DIM;
    float4 v = *(const float4*)(msa + ((size_t)(s * N_DIM + n) << 8) + (c4 << 2));
    ushort4 o;
    o.x = f2bf(v.x); o.y = f2bf(v.y); o.z = f2bf(v.z); o.w = f2bf(v.w);
    *(ushort4*)(A + ((size_t)token << 8) + (c4 << 2)) = o;
  } else {
    int tid = (b - 12288) * 256 + threadIdx.x;  // 65536 float4 units total
    const float* src; unsigned short* dst; int idx;
    if (tid < 49152) { src = wq; dst = dq; idx = tid; }
    else { src = wo; dst = do_; idx = tid - 49152; }
    float4 v = *(const float4*)(src + (size_t)idx * 4);
    ushort4 o;
    o.x = f2bf(v.x); o.y = f2bf(v.y); o.z = f2bf(v.z); o.w = f2bf(v.w);
    *(ushort4*)(dst + (size_t)idx * 4) = o;
  }
}

// ---------------- kernel 1: QKV GEMM  M=49152 N=768 K=256 ------------------
// R4-exact LDS/compute/epilogue (measured best) + R16: 1-D XCD-chunked grid
// (R10's mapping, measured FETCH 26.5MB): the 6 bn-sharers of one A-panel run
// adjacently on ONE XCD -> panel fetched once into that XCD's L2 (2-D grid
// dispatched them 384 slots apart across all 8 XCDs -> FETCH 46MB).
// Q,K stored packed [t3][nh][s][d] (C^T via swapped mfma -> ushort4 along d);
// V stored transposed [nh][d][s].
__global__ __launch_bounds__(256) void k_qkv(const unsigned short* __restrict__ A,
                                             const unsigned short* __restrict__ W,
                                             const float* __restrict__ bq,
                                             unsigned short* __restrict__ qkv) {
  __shared__ unsigned short As[128 * 64];
  __shared__ unsigned short Bs[128 * 64];
  const int tid = threadIdx.x;
  const int lane = tid & 63, wid = tid >> 6;
  const int l16 = lane & 15, lg = lane >> 4;
  const int wr = wid >> 1, wc = wid & 1;
  // XCD-chunked bm-major mapping: 2304 blocks = 8 XCDs x 288; o = bm*6+bn.
  const int p = blockIdx.x;
  const int o = (p & 7) * 288 + (p >> 3);
  const int bm0 = (o / 6) * 128;
  const int bn0 = (o % 6) * 128;
  const int lrow = lane >> 3, lchunk = lane & 7;
  const int sw = ((lchunk ^ lrow) * 8);   // pre-swizzled source chunk (elems)

  f32x4 acc[4][4] = {};

  for (int ks = 0; ks < 4; ks++) {
    const int k0 = ks * 64;
    __syncthreads();
#pragma unroll
    for (int q = 0; q < 4; q++) {
      int base_row = wid * 32 + q * 8;
      gl2lds16(A + (size_t)(bm0 + base_row + lrow) * 256 + k0 + sw, &As[base_row * 64]);
    }
#pragma unroll
    for (int q = 0; q < 4; q++) {
      int base_row = wid * 32 + q * 8;
      gl2lds16(W + (size_t)(bn0 + base_row + lrow) * 256 + k0 + sw, &Bs[base_row * 64]);
    }
    __syncthreads();
#pragma unroll
    for (int kk = 0; kk < 2; kk++) {
      const int xr = ((kk * 4 + lg) ^ (l16 & 7)) * 8;   // swizzled read chunk
      bf16x8 a[4], b[4];
#pragma unroll
      for (int m = 0; m < 4; m++)
        a[m] = *(const bf16x8*)&As[(wr * 64 + m * 16 + l16) * 64 + xr];
#pragma unroll
      for (int n2 = 0; n2 < 4; n2++)
        b[n2] = *(const bf16x8*)&Bs[(wc * 64 + n2 * 16 + l16) * 64 + xr];
      if (bn0 < 512) {   // Q/K: compute C^T (row=j, col=token)
#pragma unroll
        for (int m = 0; m < 4; m++)
#pragma unroll
          for (int n2 = 0; n2 < 4; n2++)
            acc[m][n2] = __builtin_amdgcn_mfma_f32_16x16x32_bf16(b[n2], a[m], acc[m][n2], 0, 0, 0);
      } else {           // V: normal (row=token, col=j)
#pragma unroll
        for (int m = 0; m < 4; m++)
#pragma unroll
          for (int n2 = 0; n2 < 4; n2++)
            acc[m][n2] = __builtin_amdgcn_mfma_f32_16x16x32_bf16(a[m], b[n2], acc[m][n2], 0, 0, 0);
      }
    }
  }

  const int t3 = bn0 >> 8;   // 0=Q, 1=K, 2=V
  if (t3 < 2) {
    // C^T: lane holds 4 consecutive j=(h,d0..d0+3) (rows lg*4+i), col = token (l16)
#pragma unroll
    for (int n2 = 0; n2 < 4; n2++) {
      int j0 = bn0 + wc * 64 + n2 * 16 + lg * 4;
      float4 b4 = *(const float4*)&bq[j0];
      int c0 = j0 & 255;                 // h*32 + d0
      int h = c0 >> 5, d0 = c0 & 31;
#pragma unroll
      for (int m = 0; m < 4; m++) {
        int token = bm0 + wr * 64 + m * 16 + l16;
        int n = token / S_DIM;
        int s = token - n * S_DIM;       // 16-lane group never crosses n (16|192)
        ushort4 o2;
        o2.x = f2bf(acc[m][n2][0] + b4.x);
        o2.y = f2bf(acc[m][n2][1] + b4.y);
        o2.z = f2bf(acc[m][n2][2] + b4.z);
        o2.w = f2bf(acc[m][n2][3] + b4.w);
        *(ushort4*)(qkv + (size_t)t3 * QKV_STRIDE +
                    ((size_t)((n * 8 + h) * 192 + s)) * 32 + d0) = o2;
      }
    }
  } else {
    // V^T [nh][d][s]: lane col = j -> (h,d); rows lg*4+i = 4 consecutive s
#pragma unroll
    for (int n2 = 0; n2 < 4; n2++) {
      int j = bn0 + wc * 64 + n2 * 16 + l16;
      int hd = j - 512;
      int h = hd >> 5, d = hd & 31;
      float bias = bq[j];
#pragma unroll
      for (int m = 0; m < 4; m++) {
        int t0 = bm0 + wr * 64 + m * 16 + lg * 4;
        int n = t0 / S_DIM;
        int s0 = t0 - n * S_DIM;     // 4-group never crosses n boundary (4 | 192)
        ushort4 o2;
        o2.x = f2bf(acc[m][n2][0] + bias);
        o2.y = f2bf(acc[m][n2][1] + bias);
        o2.z = f2bf(acc[m][n2][2] + bias);
        o2.w = f2bf(acc[m][n2][3] + bias);
        *(ushort4*)(qkv + (size_t)2 * QKV_STRIDE + ((size_t)(n * 8 + h) * 32 + d) * 192 + s0) = o2;
      }
    }
  }
}

// ---------------- kernel 2: attention, 6 waves (q-tiles) per (n,h) ---------
// Swapped QK^T at 32x32: S^T = mfma(K,Q) -> lane owns q-col = lane&31.
// Online softmax (defer-max), P->A-frag via cvt_pk + shfl_xor(32). No LDS.
// Q,K packed [nh][s][d]; V^T [nh][d][s]. 6 waves share K/V via L1/L2.
__global__ __launch_bounds__(384) void k_attn2(const unsigned short* __restrict__ qkv,
                                               unsigned short* __restrict__ attn_out) {
  const int lane = threadIdx.x & 63;
  const int l32 = lane & 31;
  const int hi = lane >> 5;
  const int qt = threadIdx.x >> 6;   // 0..5 (wave id = q-tile)
  const int nh = blockIdx.x;         // 0..2047
  const int n = nh >> 3, h = nh & 7;
  const unsigned short* Qp = qkv + (size_t)nh * (192 * 32);
  const unsigned short* Kp = qkv + (size_t)QKV_STRIDE + (size_t)nh * (192 * 32);
  const unsigned short* Vt = qkv + (size_t)2 * QKV_STRIDE + (size_t)nh * (32 * 192); // [d][192]
  const int q0 = qt * 32;

  // Q B-frags: lane holds col q = l32, k-dim d = hi*8+j (+16 per frag)
  bf16x8 bq0 = *(const bf16x8*)(Qp + (q0 + l32) * 32 + hi * 8);
  bf16x8 bq1 = *(const bf16x8*)(Qp + (q0 + l32) * 32 + 16 + hi * 8);

  f32x16 accO = {};
  float m_run = -1e30f, l_run = 0.f;
  const float scale = 0.17677669529663687f;          // 1/sqrt(32)
  const float DEFER = 8.0f / 0.17677669529663687f;   // raw-domain threshold

  // prefetch K and V tile 0
  bf16x8 ka0 = *(const bf16x8*)(Kp + l32 * 32 + hi * 8);
  bf16x8 ka1 = *(const bf16x8*)(Kp + l32 * 32 + 16 + hi * 8);
  bf16x8 va0 = *(const bf16x8*)(Vt + (size_t)l32 * 192 + hi * 8);
  bf16x8 va1 = *(const bf16x8*)(Vt + (size_t)l32 * 192 + 16 + hi * 8);

#pragma unroll
  for (int t = 0; t < 6; t++) {
    bf16x8 kn0, kn1, vn0, vn1;
    if (t < 5) {
      kn0 = *(const bf16x8*)(Kp + ((t + 1) * 32 + l32) * 32 + hi * 8);
      kn1 = *(const bf16x8*)(Kp + ((t + 1) * 32 + l32) * 32 + 16 + hi * 8);
      vn0 = *(const bf16x8*)(Vt + (size_t)l32 * 192 + (t + 1) * 32 + hi * 8);
      vn1 = *(const bf16x8*)(Vt + (size_t)l32 * 192 + (t + 1) * 32 + 16 + hi * 8);
    }
    // S^T[k][q]: reg r holds row k = (r&3)+8*(r>>2)+4*hi, col q = l32
    f32x16 sv = {};
    sv = __builtin_amdgcn_mfma_f32_32x32x16_bf16(ka0, bq0, sv, 0, 0, 0);
    sv = __builtin_amdgcn_mfma_f32_32x32x16_bf16(ka1, bq1, sv, 0, 0, 0);

    // tile max over full k column (own 16 + pair 16)
    float tmx = sv[0];
#pragma unroll
    for (int r = 1; r < 16; r++) tmx = fmaxf(tmx, sv[r]);
    tmx = fmaxf(tmx, __shfl_xor(tmx, 32));

    bool need = tmx > m_run + DEFER;
    if (__ballot(need)) {
      float m_new = fmaxf(m_run, tmx);
      float corr = __expf((m_run - m_new) * scale);
      l_run *= corr;
#pragma unroll
      for (int r = 0; r < 16; r++) {
        int qr = (r & 3) + 8 * (r >> 2) + 4 * hi;
        accO[r] *= __shfl(corr, qr);
      }
      m_run = m_new;
    }

    // exp + row-sum
    float ssum = 0.f;
#pragma unroll
    for (int r = 0; r < 16; r++) {
      float p2 = __expf((sv[r] - m_run) * scale);
      sv[r] = p2;
      ssum += p2;
    }
    ssum += __shfl_xor(ssum, 32);
    l_run += ssum;

    // pack P to bf16 pairs: a_g=pk[2g] rows g*8+hi*4+{0,1}; b_g=pk[2g+1] +{2,3}
    unsigned pk[8];
#pragma unroll
    for (int g = 0; g < 4; g++) {
      pk[2 * g]     = cvt_pk_bf16(sv[4 * g],     sv[4 * g + 1]);
      pk[2 * g + 1] = cvt_pk_bf16(sv[4 * g + 2], sv[4 * g + 3]);
    }

#pragma unroll
    for (int kh = 0; kh < 2; kh++) {
      // exchange: hi=0 lane needs pair's {a,b}_{2kh}; hi=1 needs pair's {a,b}_{2kh+1}
      unsigned sa = hi ? pk[4 * kh]     : pk[4 * kh + 2];
      unsigned sb = hi ? pk[4 * kh + 1] : pk[4 * kh + 3];
      unsigned pa = __shfl_xor((int)sa, 32);
      unsigned pb = __shfl_xor((int)sb, 32);
      union { unsigned u[4]; bf16x8 v; } af;
      af.u[0] = hi ? pa : pk[4 * kh];
      af.u[1] = hi ? pb : pk[4 * kh + 1];
      af.u[2] = hi ? pk[4 * kh + 2] : pa;
      af.u[3] = hi ? pk[4 * kh + 3] : pb;
      accO = __builtin_amdgcn_mfma_f32_32x32x16_bf16(af.v, kh ? va1 : va0, accO, 0, 0, 0);
    }
    ka0 = kn0; ka1 = kn1; va0 = vn0; va1 = vn1;
  }

  // epilogue: O[q][d] /= l[q]; store to attn_out[(s*256+n)*256 + h*32+d]
  float inv = 1.0f / l_run;
#pragma unroll
  for (int r = 0; r < 16; r++) {
    int qr = (r & 3) + 8 * (r >> 2) + 4 * hi;
    float v = accO[r] * __shfl(inv, qr);
    attn_out[((size_t)((q0 + qr) * 256 + n)) * 256 + h * 32 + l32] = f2bf(v);
  }
}

// ---------------- kernel 3: out-proj + residual + LayerNorm ----------------
// A = attn_out [token'=s*256+n][256] bf16, W=[256][256] bf16. BK=64 + swizzle.
// BM=64: grid 768 (3 blocks/CU), LDS 40KB, 16 f32x4 acc/thread.
__global__ __launch_bounds__(256) void k_out(const unsigned short* __restrict__ Aat,
                                             const unsigned short* __restrict__ W,
                                             const float* __restrict__ bo,
                                             const float* __restrict__ msa,
                                             const float* __restrict__ gamma,
                                             const float* __restrict__ beta,
                                             float* __restrict__ out) {
  __shared__ unsigned short As[64 * 64];
  __shared__ unsigned short Bs[256 * 64];
  const int tid = threadIdx.x;
  const int lane = tid & 63, wid = tid >> 6;
  const int l16 = lane & 15, lg = lane >> 4;
  const int bm0 = blockIdx.x * 64;
  const int lrow = lane >> 3, lchunk = lane & 7;
  const int sw = ((lchunk ^ lrow) * 8);

  f32x4 acc[16] = {};

  for (int ks = 0; ks < 4; ks++) {
    const int k0 = ks * 64;
    __syncthreads();
#pragma unroll
    for (int q = 0; q < 2; q++) {
      int base_row = q * 32 + wid * 8;
      gl2lds16(Aat + (size_t)(bm0 + base_row + lrow) * 256 + k0 + sw, &As[base_row * 64]);
    }
#pragma unroll
    for (int q = 0; q < 8; q++) {
      int base_row = wid * 64 + q * 8;
      gl2lds16(W + (size_t)(base_row + lrow) * 256 + k0 + sw, &Bs[base_row * 64]);
    }
    __syncthreads();
#pragma unroll
    for (int kk = 0; kk < 2; kk++) {
      const int xr = ((kk * 4 + lg) ^ (l16 & 7)) * 8;
      bf16x8 a = *(const bf16x8*)&As[(wid * 16 + l16) * 64 + xr];
#pragma unroll
      for (int c = 0; c < 16; c++) {
        bf16x8 b = *(const bf16x8*)&Bs[(c * 16 + l16) * 64 + xr];
        acc[c] = __builtin_amdgcn_mfma_f32_16x16x32_bf16(a, b, acc[c], 0, 0, 0);
      }
    }
  }

  // epilogue: bias + residual, then LN per row (row spread over l16 x 16 frags)
#pragma unroll
  for (int c = 0; c < 16; c++) {
    int col = c * 16 + l16;
    float bias = bo[col];
#pragma unroll
    for (int i = 0; i < 4; i++) {
      int row = bm0 + wid * 16 + lg * 4 + i;
      acc[c][i] += bias + msa[(size_t)row * 256 + col];
    }
  }
#pragma unroll
  for (int i = 0; i < 4; i++) {
    float s1 = 0.f, s2 = 0.f;
#pragma unroll
    for (int c = 0; c < 16; c++) { float x = acc[c][i]; s1 += x; s2 += x * x; }
    s1 += __shfl_xor(s1, 1); s2 += __shfl_xor(s2, 1);
    s1 += __shfl_xor(s1, 2); s2 += __shfl_xor(s2, 2);
    s1 += __shfl_xor(s1, 4); s2 += __shfl_xor(s2, 4);
    s1 += __shfl_xor(s1, 8); s2 += __shfl_xor(s2, 8);
    float mu = s1 * (1.0f / 256.0f);
    float var = s2 * (1.0f / 256.0f) - mu * mu;
    float rstd = rsqrtf(var + 1e-5f);
    int row = bm0 + wid * 16 + lg * 4 + i;
#pragma unroll
    for (int c = 0; c < 16; c++) {
      int col = c * 16 + l16;
      float y = (acc[c][i] - mu) * rstd * gamma[col] + beta[col];
      out[(size_t)row * 256 + col] = y;
    }
  }
}

extern "C" void kernel_launch(void* const* d_in, const int* in_sizes, int n_in,
                              void* d_out, int out_size, void* d_ws, size_t ws_size,
                              hipStream_t stream) {
  const float* msa   = (const float*)d_in[0];
  const float* w_qkv = (const float*)d_in[1];
  const float* b_qkv = (const float*)d_in[2];
  const float* w_out = (const float*)d_in[3];
  const float* b_out = (const float*)d_in[4];
  const float* gamma = (const float*)d_in[5];
  const float* beta  = (const float*)d_in[6];
  float* out = (float*)d_out;

  char* ws = (char*)d_ws;
  // ws layout (bytes): A/attn_out 25165824 | Q 25165824 | K .. | V^T .. | wq 393216 | wo 131072
  unsigned short* A      = (unsigned short*)(ws);                      // reused as attn_out
  unsigned short* qkvbuf = (unsigned short*)(ws + 25165824ull);
  unsigned short* wq_bf  = (unsigned short*)(ws + 4ull * 25165824ull);
  unsigned short* wo_bf  = (unsigned short*)(ws + 4ull * 25165824ull + 393216ull);

  k_prep<<<12544, 256, 0, stream>>>(msa, A, w_qkv, w_out, wq_bf, wo_bf);
  k_qkv<<<2304, 256, 0, stream>>>(A, wq_bf, b_qkv, qkvbuf);
  k_attn2<<<2048, 384, 0, stream>>>(qkvbuf, A);
  k_out<<<768, 256, 0, stream>>>(A, wo_bf, b_out, msa, gamma, beta, out);
}

// Round 17
// 121.872 us; speedup vs baseline: 1.4224x; 1.0064x over previous
//
#include <hip/hip_runtime.h>
#include <stdint.h>

// MSA column attention, B=1 S=192 N=256 C=256 H=8 D=32
#define S_DIM 192
#define N_DIM 256
#define C_DIM 256
#define H_DIM 8
#define D_DIM 32
#define QKV_STRIDE (N_DIM * H_DIM * S_DIM * D_DIM)  // 12582912 elems (one of q/k/v)

typedef float f32x4 __attribute__((ext_vector_type(4)));
typedef float f32x16 __attribute__((ext_vector_type(16)));
typedef short bf16x8 __attribute__((ext_vector_type(8)));

__device__ __forceinline__ unsigned short f2bf(float f) {
  union { float f; unsigned u; } v; v.f = f;
  unsigned r = v.u + 0x7FFFu + ((v.u >> 16) & 1u);   // RNE
  return (unsigned short)(r >> 16);
}

__device__ __forceinline__ unsigned cvt_pk_bf16(float lo, float hi) {
  unsigned r;
  asm("v_cvt_pk_bf16_f32 %0, %1, %2" : "=v"(r) : "v"(lo), "v"(hi));
  return r;
}

__device__ __forceinline__ void gl2lds16(const void* g, void* l) {
  __builtin_amdgcn_global_load_lds(
      (const __attribute__((address_space(1))) unsigned int*)g,
      (__attribute__((address_space(3))) unsigned int*)l, 16, 0, 0);
}

// ---------------- kernel 0: weight converts f32 -> bf16 (tiny) -------------
__global__ __launch_bounds__(256) void k_cvt2(const float* __restrict__ wq,
                                              const float* __restrict__ wo,
                                              unsigned short* __restrict__ dq,
                                              unsigned short* __restrict__ do_) {
  int tid = blockIdx.x * 256 + threadIdx.x;  // 65536 float4 units total
  const float* src; unsigned short* dst; int idx;
  if (tid < 49152) { src = wq; dst = dq; idx = tid; }
  else { src = wo; dst = do_; idx = tid - 49152; }
  float4 v = *(const float4*)(src + (size_t)idx * 4);
  ushort4 o;
  o.x = f2bf(v.x); o.y = f2bf(v.y); o.z = f2bf(v.z); o.w = f2bf(v.w);
  *(ushort4*)(dst + (size_t)idx * 4) = o;
}

// ---------------- kernel 1: QKV GEMM  M=49152 N=768 K=256 ------------------
// R17: A-operand DMA'd DIRECTLY from msa f32 via gl2lds with per-lane source
// addressing (the transpose + swizzle folded into the source address; LDS
// dest stays linear — m173 pattern, proven by our own B-staging). f32 tile
// staged in LDS (32KB), converted to bf16 at fragment-read (2x ds_read_b128
// + 4 cvt_pk per frag; chunk16 ^= row&15 swizzle -> 2-way reads, free).
// Eliminates k_prep's msa pass + the 24MB A buffer round-trip entirely.
// Rest R16-exact: XCD-chunked 1-D grid, BK=64 single-buffered, B via bf16
// gl2lds + sw swizzle. Q,K packed [t3][nh][s][d] (C^T epilogue); V^T [nh][d][s].
__global__ __launch_bounds__(256) void k_qkv(const float* __restrict__ msa,
                                             const unsigned short* __restrict__ W,
                                             const float* __restrict__ bq,
                                             unsigned short* __restrict__ qkv) {
  __shared__ float Asf[128 * 64];           // 32KB f32 A-tile, chunk-swizzled
  __shared__ unsigned short Bs[128 * 64];   // 16KB bf16 B-tile
  const int tid = threadIdx.x;
  const int lane = tid & 63, wid = tid >> 6;
  const int l16 = lane & 15, lg = lane >> 4;
  const int wr = wid >> 1, wc = wid & 1;
  // XCD-chunked bm-major mapping: 2304 blocks = 8 XCDs x 288; o = bm*6+bn.
  const int p = blockIdx.x;
  const int o = (p & 7) * 288 + (p >> 3);
  const int bm0 = (o / 6) * 128;
  const int bn0 = (o % 6) * 128;
  const int lrow = lane >> 3, lchunk = lane & 7;
  const int sw = ((lchunk ^ lrow) * 8);   // B: pre-swizzled source chunk (elems)

  f32x4 acc[4][4] = {};

  for (int ks = 0; ks < 4; ks++) {
    const int k0 = ks * 64;
    __syncthreads();
    // A: 128 rows x 64 f32 (256B/row); 8 gl2lds per thread; per-lane source
    // from msa[(s*256+n)*256 + k0 + lc*4] with lc = c16 ^ (row&15) (involution
    // with the read-side swizzle); LDS dest linear.
#pragma unroll
    for (int q = 0; q < 8; q++) {
      int base_row = wid * 32 + q * 4;
      int row = base_row + (lane >> 4);
      int token = bm0 + row;
      int nn = token / S_DIM;
      int ss = token - nn * S_DIM;
      int lc = (lane & 15) ^ (row & 15);
      gl2lds16(msa + (size_t)(ss * 256 + nn) * 256 + k0 + lc * 4,
               &Asf[base_row * 64]);
    }
    // B: bf16, 128 rows x 64 (128B/row), 4 gl2lds per thread (unchanged)
#pragma unroll
    for (int q = 0; q < 4; q++) {
      int base_row = wid * 32 + q * 8;
      gl2lds16(W + (size_t)(bn0 + base_row + lrow) * 256 + k0 + sw, &Bs[base_row * 64]);
    }
    __syncthreads();
#pragma unroll
    for (int kk = 0; kk < 2; kk++) {
      const int xr = ((kk * 4 + lg) ^ (l16 & 7)) * 8;   // B swizzled read chunk
      bf16x8 a[4], b[4];
#pragma unroll
      for (int m = 0; m < 4; m++) {
        int R = wr * 64 + m * 16 + l16;                 // R&15 == l16
        int p1 = (2 * (kk * 4 + lg)) ^ l16;             // physical 16B chunk
        int p2 = p1 ^ 1;
        f32x4 d0 = *(const f32x4*)((const char*)Asf + R * 256 + p1 * 16);
        f32x4 d1 = *(const f32x4*)((const char*)Asf + R * 256 + p2 * 16);
        union { unsigned u[4]; bf16x8 v; } t;
        t.u[0] = cvt_pk_bf16(d0[0], d0[1]);
        t.u[1] = cvt_pk_bf16(d0[2], d0[3]);
        t.u[2] = cvt_pk_bf16(d1[0], d1[1]);
        t.u[3] = cvt_pk_bf16(d1[2], d1[3]);
        a[m] = t.v;
      }
#pragma unroll
      for (int n2 = 0; n2 < 4; n2++)
        b[n2] = *(const bf16x8*)&Bs[(wc * 64 + n2 * 16 + l16) * 64 + xr];
      if (bn0 < 512) {   // Q/K: compute C^T (row=j, col=token)
#pragma unroll
        for (int m = 0; m < 4; m++)
#pragma unroll
          for (int n2 = 0; n2 < 4; n2++)
            acc[m][n2] = __builtin_amdgcn_mfma_f32_16x16x32_bf16(b[n2], a[m], acc[m][n2], 0, 0, 0);
      } else {           // V: normal (row=token, col=j)
#pragma unroll
        for (int m = 0; m < 4; m++)
#pragma unroll
          for (int n2 = 0; n2 < 4; n2++)
            acc[m][n2] = __builtin_amdgcn_mfma_f32_16x16x32_bf16(a[m], b[n2], acc[m][n2], 0, 0, 0);
      }
    }
  }

  const int t3 = bn0 >> 8;   // 0=Q, 1=K, 2=V
  if (t3 < 2) {
    // C^T: lane holds 4 consecutive j=(h,d0..d0+3) (rows lg*4+i), col = token (l16)
#pragma unroll
    for (int n2 = 0; n2 < 4; n2++) {
      int j0 = bn0 + wc * 64 + n2 * 16 + lg * 4;
      float4 b4 = *(const float4*)&bq[j0];
      int c0 = j0 & 255;                 // h*32 + d0
      int h = c0 >> 5, d0 = c0 & 31;
#pragma unroll
      for (int m = 0; m < 4; m++) {
        int token = bm0 + wr * 64 + m * 16 + l16;
        int n = token / S_DIM;
        int s = token - n * S_DIM;       // 16-lane group never crosses n (16|192)
        ushort4 o2;
        o2.x = f2bf(acc[m][n2][0] + b4.x);
        o2.y = f2bf(acc[m][n2][1] + b4.y);
        o2.z = f2bf(acc[m][n2][2] + b4.z);
        o2.w = f2bf(acc[m][n2][3] + b4.w);
        *(ushort4*)(qkv + (size_t)t3 * QKV_STRIDE +
                    ((size_t)((n * 8 + h) * 192 + s)) * 32 + d0) = o2;
      }
    }
  } else {
    // V^T [nh][d][s]: lane col = j -> (h,d); rows lg*4+i = 4 consecutive s
#pragma unroll
    for (int n2 = 0; n2 < 4; n2++) {
      int j = bn0 + wc * 64 + n2 * 16 + l16;
      int hd = j - 512;
      int h = hd >> 5, d = hd & 31;
      float bias = bq[j];
#pragma unroll
      for (int m = 0; m < 4; m++) {
        int t0 = bm0 + wr * 64 + m * 16 + lg * 4;
        int n = t0 / S_DIM;
        int s0 = t0 - n * S_DIM;     // 4-group never crosses n boundary (4 | 192)
        ushort4 o2;
        o2.x = f2bf(acc[m][n2][0] + bias);
        o2.y = f2bf(acc[m][n2][1] + bias);
        o2.z = f2bf(acc[m][n2][2] + bias);
        o2.w = f2bf(acc[m][n2][3] + bias);
        *(ushort4*)(qkv + (size_t)2 * QKV_STRIDE + ((size_t)(n * 8 + h) * 32 + d) * 192 + s0) = o2;
      }
    }
  }
}

// ---------------- kernel 2: attention, 6 waves (q-tiles) per (n,h) ---------
// Swapped QK^T at 32x32: S^T = mfma(K,Q) -> lane owns q-col = lane&31.
// Online softmax (defer-max), P->A-frag via cvt_pk + shfl_xor(32). No LDS.
// Q,K packed [nh][s][d]; V^T [nh][d][s]. 6 waves share K/V via L1/L2.
__global__ __launch_bounds__(384) void k_attn2(const unsigned short* __restrict__ qkv,
                                               unsigned short* __restrict__ attn_out) {
  const int lane = threadIdx.x & 63;
  const int l32 = lane & 31;
  const int hi = lane >> 5;
  const int qt = threadIdx.x >> 6;   // 0..5 (wave id = q-tile)
  const int nh = blockIdx.x;         // 0..2047
  const int n = nh >> 3, h = nh & 7;
  const unsigned short* Qp = qkv + (size_t)nh * (192 * 32);
  const unsigned short* Kp = qkv + (size_t)QKV_STRIDE + (size_t)nh * (192 * 32);
  const unsigned short* Vt = qkv + (size_t)2 * QKV_STRIDE + (size_t)nh * (32 * 192); // [d][192]
  const int q0 = qt * 32;

  // Q B-frags: lane holds col q = l32, k-dim d = hi*8+j (+16 per frag)
  bf16x8 bq0 = *(const bf16x8*)(Qp + (q0 + l32) * 32 + hi * 8);
  bf16x8 bq1 = *(const bf16x8*)(Qp + (q0 + l32) * 32 + 16 + hi * 8);

  f32x16 accO = {};
  float m_run = -1e30f, l_run = 0.f;
  const float scale = 0.17677669529663687f;          // 1/sqrt(32)
  const float DEFER = 8.0f / 0.17677669529663687f;   // raw-domain threshold

  // prefetch K and V tile 0
  bf16x8 ka0 = *(const bf16x8*)(Kp + l32 * 32 + hi * 8);
  bf16x8 ka1 = *(const bf16x8*)(Kp + l32 * 32 + 16 + hi * 8);
  bf16x8 va0 = *(const bf16x8*)(Vt + (size_t)l32 * 192 + hi * 8);
  bf16x8 va1 = *(const bf16x8*)(Vt + (size_t)l32 * 192 + 16 + hi * 8);

#pragma unroll
  for (int t = 0; t < 6; t++) {
    bf16x8 kn0, kn1, vn0, vn1;
    if (t < 5) {
      kn0 = *(const bf16x8*)(Kp + ((t + 1) * 32 + l32) * 32 + hi * 8);
      kn1 = *(const bf16x8*)(Kp + ((t + 1) * 32 + l32) * 32 + 16 + hi * 8);
      vn0 = *(const bf16x8*)(Vt + (size_t)l32 * 192 + (t + 1) * 32 + hi * 8);
      vn1 = *(const bf16x8*)(Vt + (size_t)l32 * 192 + (t + 1) * 32 + 16 + hi * 8);
    }
    // S^T[k][q]: reg r holds row k = (r&3)+8*(r>>2)+4*hi, col q = l32
    f32x16 sv = {};
    sv = __builtin_amdgcn_mfma_f32_32x32x16_bf16(ka0, bq0, sv, 0, 0, 0);
    sv = __builtin_amdgcn_mfma_f32_32x32x16_bf16(ka1, bq1, sv, 0, 0, 0);

    // tile max over full k column (own 16 + pair 16)
    float tmx = sv[0];
#pragma unroll
    for (int r = 1; r < 16; r++) tmx = fmaxf(tmx, sv[r]);
    tmx = fmaxf(tmx, __shfl_xor(tmx, 32));

    bool need = tmx > m_run + DEFER;
    if (__ballot(need)) {
      float m_new = fmaxf(m_run, tmx);
      float corr = __expf((m_run - m_new) * scale);
      l_run *= corr;
#pragma unroll
      for (int r = 0; r < 16; r++) {
        int qr = (r & 3) + 8 * (r >> 2) + 4 * hi;
        accO[r] *= __shfl(corr, qr);
      }
      m_run = m_new;
    }

    // exp + row-sum
    float ssum = 0.f;
#pragma unroll
    for (int r = 0; r < 16; r++) {
      float p2 = __expf((sv[r] - m_run) * scale);
      sv[r] = p2;
      ssum += p2;
    }
    ssum += __shfl_xor(ssum, 32);
    l_run += ssum;

    // pack P to bf16 pairs: a_g=pk[2g] rows g*8+hi*4+{0,1}; b_g=pk[2g+1] +{2,3}
    unsigned pk[8];
#pragma unroll
    for (int g = 0; g < 4; g++) {
      pk[2 * g]     = cvt_pk_bf16(sv[4 * g],     sv[4 * g + 1]);
      pk[2 * g + 1] = cvt_pk_bf16(sv[4 * g + 2], sv[4 * g + 3]);
    }

#pragma unroll
    for (int kh = 0; kh < 2; kh++) {
      // exchange: hi=0 lane needs pair's {a,b}_{2kh}; hi=1 needs pair's {a,b}_{2kh+1}
      unsigned sa = hi ? pk[4 * kh]     : pk[4 * kh + 2];
      unsigned sb = hi ? pk[4 * kh + 1] : pk[4 * kh + 3];
      unsigned pa = __shfl_xor((int)sa, 32);
      unsigned pb = __shfl_xor((int)sb, 32);
      union { unsigned u[4]; bf16x8 v; } af;
      af.u[0] = hi ? pa : pk[4 * kh];
      af.u[1] = hi ? pb : pk[4 * kh + 1];
      af.u[2] = hi ? pk[4 * kh + 2] : pa;
      af.u[3] = hi ? pk[4 * kh + 3] : pb;
      accO = __builtin_amdgcn_mfma_f32_32x32x16_bf16(af.v, kh ? va1 : va0, accO, 0, 0, 0);
    }
    ka0 = kn0; ka1 = kn1; va0 = vn0; va1 = vn1;
  }

  // epilogue: O[q][d] /= l[q]; store to attn_out[(s*256+n)*256 + h*32+d]
  float inv = 1.0f / l_run;
#pragma unroll
  for (int r = 0; r < 16; r++) {
    int qr = (r & 3) + 8 * (r >> 2) + 4 * hi;
    float v = accO[r] * __shfl(inv, qr);
    attn_out[((size_t)((q0 + qr) * 256 + n)) * 256 + h * 32 + l32] = f2bf(v);
  }
}

// ---------------- kernel 3: out-proj + residual + LayerNorm ----------------
// A = attn_out [token'=s*256+n][256] bf16, W=[256][256] bf16. BK=64 + swizzle.
// BM=64: grid 768 (3 blocks/CU), LDS 40KB, 16 f32x4 acc/thread.
__global__ __launch_bounds__(256) void k_out(const unsigned short* __restrict__ Aat,
                                             const unsigned short* __restrict__ W,
                                             const float* __restrict__ bo,
                                             const float* __restrict__ msa,
                                             const float* __restrict__ gamma,
                                             const float* __restrict__ beta,
                                             float* __restrict__ out) {
  __shared__ unsigned short As[64 * 64];
  __shared__ unsigned short Bs[256 * 64];
  const int tid = threadIdx.x;
  const int lane = tid & 63, wid = tid >> 6;
  const int l16 = lane & 15, lg = lane >> 4;
  const int bm0 = blockIdx.x * 64;
  const int lrow = lane >> 3, lchunk = lane & 7;
  const int sw = ((lchunk ^ lrow) * 8);

  f32x4 acc[16] = {};

  for (int ks = 0; ks < 4; ks++) {
    const int k0 = ks * 64;
    __syncthreads();
#pragma unroll
    for (int q = 0; q < 2; q++) {
      int base_row = q * 32 + wid * 8;
      gl2lds16(Aat + (size_t)(bm0 + base_row + lrow) * 256 + k0 + sw, &As[base_row * 64]);
    }
#pragma unroll
    for (int q = 0; q < 8; q++) {
      int base_row = wid * 64 + q * 8;
      gl2lds16(W + (size_t)(base_row + lrow) * 256 + k0 + sw, &Bs[base_row * 64]);
    }
    __syncthreads();
#pragma unroll
    for (int kk = 0; kk < 2; kk++) {
      const int xr = ((kk * 4 + lg) ^ (l16 & 7)) * 8;
      bf16x8 a = *(const bf16x8*)&As[(wid * 16 + l16) * 64 + xr];
#pragma unroll
      for (int c = 0; c < 16; c++) {
        bf16x8 b = *(const bf16x8*)&Bs[(c * 16 + l16) * 64 + xr];
        acc[c] = __builtin_amdgcn_mfma_f32_16x16x32_bf16(a, b, acc[c], 0, 0, 0);
      }
    }
  }

  // epilogue: bias + residual, then LN per row (row spread over l16 x 16 frags)
#pragma unroll
  for (int c = 0; c < 16; c++) {
    int col = c * 16 + l16;
    float bias = bo[col];
#pragma unroll
    for (int i = 0; i < 4; i++) {
      int row = bm0 + wid * 16 + lg * 4 + i;
      acc[c][i] += bias + msa[(size_t)row * 256 + col];
    }
  }
#pragma unroll
  for (int i = 0; i < 4; i++) {
    float s1 = 0.f, s2 = 0.f;
#pragma unroll
    for (int c = 0; c < 16; c++) { float x = acc[c][i]; s1 += x; s2 += x * x; }
    s1 += __shfl_xor(s1, 1); s2 += __shfl_xor(s2, 1);
    s1 += __shfl_xor(s1, 2); s2 += __shfl_xor(s2, 2);
    s1 += __shfl_xor(s1, 4); s2 += __shfl_xor(s2, 4);
    s1 += __shfl_xor(s1, 8); s2 += __shfl_xor(s2, 8);
    float mu = s1 * (1.0f / 256.0f);
    float var = s2 * (1.0f / 256.0f) - mu * mu;
    float rstd = rsqrtf(var + 1e-5f);
    int row = bm0 + wid * 16 + lg * 4 + i;
#pragma unroll
    for (int c = 0; c < 16; c++) {
      int col = c * 16 + l16;
      float y = (acc[c][i] - mu) * rstd * gamma[col] + beta[col];
      out[(size_t)row * 256 + col] = y;
    }
  }
}

extern "C" void kernel_launch(void* const* d_in, const int* in_sizes, int n_in,
                              void* d_out, int out_size, void* d_ws, size_t ws_size,
                              hipStream_t stream) {
  const float* msa   = (const float*)d_in[0];
  const float* w_qkv = (const float*)d_in[1];
  const float* b_qkv = (const float*)d_in[2];
  const float* w_out = (const float*)d_in[3];
  const float* b_out = (const float*)d_in[4];
  const float* gamma = (const float*)d_in[5];
  const float* beta  = (const float*)d_in[6];
  float* out = (float*)d_out;

  char* ws = (char*)d_ws;
  // ws layout (bytes): qkv 75497472 | attn 25165824 | wq 393216 | wo 131072
  unsigned short* qkvbuf = (unsigned short*)(ws);
  unsigned short* attn   = (unsigned short*)(ws + 75497472ull);
  unsigned short* wq_bf  = (unsigned short*)(ws + 75497472ull + 25165824ull);
  unsigned short* wo_bf  = (unsigned short*)(ws + 75497472ull + 25165824ull + 393216ull);

  k_cvt2<<<256, 256, 0, stream>>>(w_qkv, w_out, wq_bf, wo_bf);
  k_qkv<<<2304, 256, 0, stream>>>(msa, wq_bf, b_qkv, qkvbuf);
  k_attn2<<<2048, 384, 0, stream>>>(qkvbuf, attn);
  k_out<<<768, 256, 0, stream>>>(attn, wo_bf, b_out, msa, gamma, beta, out);
}